// Round 6
// baseline (310.226 us; speedup 1.0000x reference)
//
#include <hip/hip_runtime.h>
#include <stdint.h>

typedef unsigned short u16;
typedef __attribute__((ext_vector_type(4))) u16 u16x4;
typedef __attribute__((ext_vector_type(8))) u16 u16x8;
typedef __attribute__((ext_vector_type(8))) __bf16 bf16x8;
typedef __attribute__((ext_vector_type(4))) float f32x4;

#define D_MODEL 2048
#define N_HEADS 16
#define HEAD_DIM 128
#define BATCH 2
#define SEQ 2048
#define M_TOT (BATCH*SEQ)          // 4096
#define N_QKV (3*D_MODEL)          // 6144

__device__ __forceinline__ u16 f2b(float f) {
  union { float f; uint32_t u; } c; c.f = f;
  uint32_t u = c.u;
  uint32_t r = (u + 0x7fffu + ((u >> 16) & 1u)) >> 16;
  return (u16)r;
}

__device__ __forceinline__ void gl_lds16(const u16* g, u16* l) {
  __builtin_amdgcn_global_load_lds(
      (const __attribute__((address_space(1))) uint32_t*)g,
      (__attribute__((address_space(3))) uint32_t*)l, 16, 0, 0);
}

template <int N> __device__ __forceinline__ void waitvm() {
  if constexpr (N == 8)      asm volatile("s_waitcnt vmcnt(8)" ::: "memory");
  else if constexpr (N == 6) asm volatile("s_waitcnt vmcnt(6)" ::: "memory");
  else if constexpr (N == 4) asm volatile("s_waitcnt vmcnt(4)" ::: "memory");
  else if constexpr (N == 3) asm volatile("s_waitcnt vmcnt(3)" ::: "memory");
  else                       asm volatile("s_waitcnt vmcnt(0)" ::: "memory");
}

// ---------------- prep kernels ----------------

__global__ void cast_x_kernel(const float* __restrict__ x, u16* __restrict__ xb, int n) {
  int i = (blockIdx.x * blockDim.x + threadIdx.x) * 4;
  if (i >= n) return;
  f32x4 v = *(const f32x4*)(x + i);
  u16x4 o;
  o[0] = f2b(v[0]); o[1] = f2b(v[1]); o[2] = f2b(v[2]); o[3] = f2b(v[3]);
  *(u16x4*)(xb + i) = o;
}

// Wq/Wk/Wv [H][2048][128] f32  ->  Wt [6144][2048] bf16, row n=(qkv*2048+h*128+d), K-major
__global__ void trans_wqkv_kernel(const float* __restrict__ Wq, const float* __restrict__ Wk,
                                  const float* __restrict__ Wv, u16* __restrict__ Wt) {
  __shared__ u16 Tl[128][72];
  const int hh = blockIdx.y;           // 0..47 = qkv*16+h
  const int qkv = hh >> 4, h = hh & 15;
  const float* src = (qkv == 0 ? Wq : qkv == 1 ? Wk : Wv) + (size_t)h * 2048 * 128;
  const int k0 = blockIdx.x * 64;
  const int tid = threadIdx.x;
  for (int it = 0; it < 32; ++it) {
    int idx = it * 256 + tid;
    int k = idx >> 7, d = idx & 127;
    Tl[d][k] = f2b(src[(size_t)(k0 + k) * 128 + d]);
  }
  __syncthreads();
  for (int it = 0; it < 32; ++it) {
    int idx = it * 256 + tid;
    int d = idx >> 6, kk = idx & 63;
    Wt[(size_t)(hh * 128 + d) * 2048 + k0 + kk] = Tl[d][kk];
  }
}

// Wo [2048][2048] f32 -> Wot [2048][2048] bf16 (transposed, K-major)
__global__ void trans_wo_kernel(const float* __restrict__ Wo, u16* __restrict__ Wot) {
  __shared__ u16 Tl[128][72];
  const int k0 = blockIdx.x * 64;     // 32 tiles
  const int n0 = blockIdx.y * 128;    // 16 tiles
  const int tid = threadIdx.x;
  for (int it = 0; it < 32; ++it) {
    int idx = it * 256 + tid;
    int k = idx >> 7, n = idx & 127;
    Tl[n][k] = f2b(Wo[(size_t)(k0 + k) * 2048 + n0 + n]);
  }
  __syncthreads();
  for (int it = 0; it < 32; ++it) {
    int idx = it * 256 + tid;
    int d = idx >> 6, kk = idx & 63;
    Wot[(size_t)(n0 + d) * 2048 + k0 + kk] = Tl[d][kk];
  }
}

// vb [B,H,T,128] bf16 -> vt [B,H,128,T] bf16 with sigma-permuted columns within
// each 64-tile: sigma(t) = (t&15)*4 + (t>>4). Matches attn's packed-P k-space.
__global__ void transpose_v_kernel(const u16* __restrict__ vb, u16* __restrict__ vt) {
  __shared__ u16 Tl[128 * 65];
  const int bh = blockIdx.y;
  const int t0 = blockIdx.x * 64;
  const int tid = threadIdx.x;
  const u16* src = vb + (size_t)bh * 2048 * 128;
  u16* dstp = vt + (size_t)bh * 128 * 2048;
#pragma unroll
  for (int c = 0; c < 4; ++c) {
    int ci = c * 256 + tid;
    int tr = ci >> 4, d0 = (ci & 15) * 8;
    u16x8 v = *(const u16x8*)(src + (size_t)(t0 + tr) * 128 + d0);
#pragma unroll
    for (int e = 0; e < 8; ++e) Tl[(d0 + e) * 65 + tr] = v[e];
  }
  __syncthreads();
#pragma unroll
  for (int it = 0; it < 32; ++it) {
    int idx = it * 256 + tid;
    int d = idx >> 6, tt = idx & 63;
    dstp[(size_t)d * 2048 + t0 + ((tt & 15) * 4 + (tt >> 4))] = Tl[d * 65 + tt];
  }
}

// ---------------- GEMM: BMx256 tile, k-half phased ring-4, counted vmcnt ----------------
// 512 threads = 8 waves (2M x 4N), per-wave (BM/2)x64 output (IM x 4 fragments).
// LDS: 4 ring slots, each = one k-half {A BMx32, B 256x32} bf16, 64-B rows,
// XOR-swizzle byte ^= ((row>>1)&3)<<4 (bits 4-5, bank-exact for 16-row b128 reads),
// staged by global_load_lds with the same involution pre-applied to the source.
// Phase h computes k-half h from slot h&3 and stages k-half h+3 into slot (h+3)&3
// (= slot h-1, whose reads finished at the previous barrier). Steady state keeps
// 2 half-stages in flight -> s_waitcnt vmcnt(2*LP); drain only in the last 3 phases.
template <int EPI, int BM>
__global__ __launch_bounds__(512, 2) void gemm256_kernel(
    const u16* __restrict__ A, const u16* __restrict__ B,
    u16* __restrict__ qo, u16* __restrict__ ko, u16* __restrict__ vo,
    const float* __restrict__ bq, const float* __restrict__ bk, const float* __restrict__ bv,
    float* __restrict__ outf, const float* __restrict__ bo) {
  constexpr int IM  = BM / 32;          // A fragments per wave (8 or 4)
  constexpr int LPA = BM / 128;         // A gl_lds per thread per phase (2 or 1)
  constexpr int LP  = LPA + 2;          // total gl_lds per thread per phase
  constexpr int ASZ = BM * 32;          // u16 per A slot
  constexpr int BSZ = 256 * 32;         // u16 per B slot
  __shared__ u16 HA[4 * ASZ];
  __shared__ u16 HB[4 * BSZ];

  constexpr int NX = (EPI == 0) ? 24 : 8;
  const int nwg = gridDim.x, q8 = nwg >> 3, bid0 = blockIdx.x;
  const int gid = (bid0 & 7) * q8 + (bid0 >> 3);   // XCD-chunked, bijective
  const int m0 = (gid / NX) * BM, n0 = (gid % NX) * 256;

  const int tid = threadIdx.x;
  const int lane = tid & 63, w = tid >> 6;
  const int wm = (w >> 2) * (BM / 2), wn = (w & 3) * 64;
  const int lr = lane & 15;
  const int ck = (lane >> 4) * 16;      // byte col of this lane's 16-B fragment chunk

  // staging: LDS linear chunk ci=(row,j) holds global chunk (row, j ^ ((row>>1)&3))
  int aoff[LPA], adst[LPA], boff[2], bdst[2];
#pragma unroll
  for (int l = 0; l < LPA; ++l) {
    int ci = l * 512 + tid, row = ci >> 2, j = ci & 3;
    aoff[l] = (m0 + row) * 2048 + (j ^ ((row >> 1) & 3)) * 8;
    adst[l] = ci * 8;
  }
#pragma unroll
  for (int l = 0; l < 2; ++l) {
    int ci = l * 512 + tid, row = ci >> 2, j = ci & 3;
    boff[l] = (n0 + row) * 2048 + (j ^ ((row >> 1) & 3)) * 8;
    bdst[l] = ci * 8;
  }

  f32x4 acc[IM][4];
  const f32x4 zero = {0.f, 0.f, 0.f, 0.f};
#pragma unroll
  for (int i = 0; i < IM; ++i)
#pragma unroll
    for (int j = 0; j < 4; ++j) acc[i][j] = zero;

  // prologue: stage k-halves 0,1,2 into slots 0,1,2
#pragma unroll
  for (int s = 0; s < 3; ++s) {
#pragma unroll
    for (int l = 0; l < LPA; ++l) gl_lds16(A + aoff[l] + s * 32, HA + s * ASZ + adst[l]);
#pragma unroll
    for (int l = 0; l < 2; ++l)   gl_lds16(B + boff[l] + s * 32, HB + s * BSZ + bdst[l]);
  }
  waitvm<2 * LP>();
  __builtin_amdgcn_s_barrier();

#define GPHASE(S, S3, DOSTAGE, H)                                                         \
  {                                                                                       \
    if (DOSTAGE) {                                                                        \
      const int k2 = (H + 3) * 32;                                                        \
      _Pragma("unroll")                                                                   \
      for (int l = 0; l < LPA; ++l) gl_lds16(A + aoff[l] + k2, HA + (S3) * ASZ + adst[l]);\
      _Pragma("unroll")                                                                   \
      for (int l = 0; l < 2; ++l)   gl_lds16(B + boff[l] + k2, HB + (S3) * BSZ + bdst[l]);\
    }                                                                                     \
    const char* Ac = (const char*)(HA + (S) * ASZ);                                       \
    const char* Bc = (const char*)(HB + (S) * BSZ);                                       \
    bf16x8 af[IM], bfr[4];                                                                \
    _Pragma("unroll")                                                                     \
    for (int i = 0; i < IM; ++i) {                                                        \
      int r = wm + i * 16 + lr;                                                           \
      af[i] = *(const bf16x8*)(Ac + r * 64 + (ck ^ (((r >> 1) & 3) << 4)));               \
    }                                                                                     \
    _Pragma("unroll")                                                                     \
    for (int j = 0; j < 4; ++j) {                                                         \
      int r = wn + j * 16 + lr;                                                           \
      bfr[j] = *(const bf16x8*)(Bc + r * 64 + (ck ^ (((r >> 1) & 3) << 4)));              \
    }                                                                                     \
    __builtin_amdgcn_s_setprio(1);                                                        \
    _Pragma("unroll")                                                                     \
    for (int i = 0; i < IM; ++i)                                                          \
      _Pragma("unroll")                                                                   \
      for (int j = 0; j < 4; ++j)                                                         \
        acc[i][j] = __builtin_amdgcn_mfma_f32_16x16x32_bf16(af[i], bfr[j], acc[i][j], 0, 0, 0); \
    __builtin_amdgcn_s_setprio(0);                                                        \
  }

  for (int kt = 0; kt < 15; ++kt) {
    const int h0 = kt * 4;
    GPHASE(0, 3, true, h0 + 0); waitvm<2 * LP>(); __builtin_amdgcn_s_barrier();
    GPHASE(1, 0, true, h0 + 1); waitvm<2 * LP>(); __builtin_amdgcn_s_barrier();
    GPHASE(2, 1, true, h0 + 2); waitvm<2 * LP>(); __builtin_amdgcn_s_barrier();
    GPHASE(3, 2, true, h0 + 3); waitvm<2 * LP>(); __builtin_amdgcn_s_barrier();
  }
  // tail: halves 60..63
  GPHASE(0, 3, true,  60); waitvm<2 * LP>(); __builtin_amdgcn_s_barrier();
  GPHASE(1, 0, false, 61); waitvm<LP>();     __builtin_amdgcn_s_barrier();
  GPHASE(2, 0, false, 62); waitvm<0>();      __builtin_amdgcn_s_barrier();
  GPHASE(3, 0, false, 63);
#undef GPHASE

  const int rbase = (lane >> 4) * 4;
  if (EPI == 0) {
    const int qkv = n0 >> 11;
    const float* bias = (qkv == 0) ? bq : (qkv == 1) ? bk : bv;
    u16* dst = (qkv == 0) ? qo : (qkv == 1) ? ko : vo;
    const float qscale = 0.08838834764831845f * 1.4426950408889634f;  // 1/sqrt(128)*log2e
#pragma unroll
    for (int i = 0; i < IM; ++i)
#pragma unroll
      for (int j = 0; j < 4; ++j)
#pragma unroll
        for (int r = 0; r < 4; ++r) {
          int gm = m0 + wm + i * 16 + rbase + r;
          int n = n0 + wn + j * 16 + lr;
          int h = (n >> 7) & 15, d = n & 127;
          float val = acc[i][j][r] + bias[n & 2047];
          if (qkv == 0) val *= qscale;
          int b = gm >> 11, t = gm & 2047;
          dst[((size_t)(b * 16 + h) * 2048 + t) * 128 + d] = f2b(val);
        }
  } else {
#pragma unroll
    for (int i = 0; i < IM; ++i)
#pragma unroll
      for (int j = 0; j < 4; ++j)
#pragma unroll
        for (int r = 0; r < 4; ++r) {
          int gm = m0 + wm + i * 16 + rbase + r;
          int gn = n0 + wn + j * 16 + lr;
          outf[(size_t)gm * 2048 + gn] = acc[i][j][r] + bo[gn];
        }
  }
}

// ---------------- flash attention (causal) ----------------
// 512 blocks of 256 threads; bid -> bh = bid&31 (XCD-grouped), qt = 15-(bid>>5)
// (heaviest blocks dispatch first; 2 blocks/CU co-resident at 80KB LDS).
// 4 waves x 32 q-rows; KV tile 64, double-buffered, gl_lds staging pre-swizzled.
// Softmax: per-lane partial row-sums (reduced once at end), defer-max with
// lane-local check (no per-tile shuffles on common path), packed b64 P stores
// in sigma-permuted k-space matching the sigma-permuted V^T.
// Q arrives pre-scaled by 1/sqrt(128)*log2e -> scores in exp2 domain.
__global__ __launch_bounds__(256) void attn_kernel(
    const u16* __restrict__ qg, const u16* __restrict__ kg,
    const u16* __restrict__ vtg, u16* __restrict__ y) {
  __shared__ u16 Kb[2][64 * 128];
  __shared__ u16 Vb[2][128 * 64];
  __shared__ u16 Pl[4][32 * 64];
  const int tid = threadIdx.x, lane = tid & 63, w = tid >> 6;
  const int bid = blockIdx.x;
  const int bh = bid & 31, qt = 15 - (bid >> 5);
  const int b = bh >> 4, h = bh & 15;
  const int lr = lane & 15, lk = (lane >> 4) * 8;
  const u16* Qp = qg + (size_t)bh * (2048 * 128);
  const u16* Kp = kg + (size_t)bh * (2048 * 128);
  const u16* Vp = vtg + (size_t)bh * (128 * 2048);

  int koff[4], voff[4], dstc[4];
#pragma unroll
  for (int c = 0; c < 4; ++c) {
    int ci = c * 256 + tid;
    dstc[c] = ci * 8;
    int kr = ci >> 4, kj = ci & 15;                 // K tile: 64 rows x 16 chunks
    koff[c] = kr * 128 + (kj ^ (kr & 7)) * 8;
    int vd = ci >> 3, vj = ci & 7;                  // V^T tile: 128 rows x 8 chunks
    voff[c] = vd * 2048 + (vj ^ (vd & 7)) * 8;
  }
  const int kxor = (lr & 7) << 4;
  const int rbase = (lane >> 4) * 4;
  const f32x4 zero = {0.f, 0.f, 0.f, 0.f};

  const int q0 = qt * 128;
  const int qw = q0 + w * 32;
  const int nt = 2 * qt + 2;

  bf16x8 qf[2][4];
#pragma unroll
  for (int s = 0; s < 2; ++s)
#pragma unroll
    for (int i = 0; i < 4; ++i)
      qf[s][i] = *(const bf16x8*)(Qp + (size_t)(qw + s * 16 + lr) * 128 + i * 32 + lk);

  f32x4 o[2][8];
#pragma unroll
  for (int s = 0; s < 2; ++s)
#pragma unroll
    for (int f = 0; f < 8; ++f) o[s][f] = zero;
  float mrow[2][4], lrow[2][4];
#pragma unroll
  for (int s = 0; s < 2; ++s)
#pragma unroll
    for (int r = 0; r < 4; ++r) { mrow[s][r] = -1e30f; lrow[s][r] = 0.f; }

  // prologue: stage tile 0
#pragma unroll
  for (int c = 0; c < 4; ++c) gl_lds16(Kp + koff[c], Kb[0] + dstc[c]);
#pragma unroll
  for (int c = 0; c < 4; ++c) gl_lds16(Vp + voff[c], Vb[0] + dstc[c]);
  __syncthreads();

  int cur = 0;
  for (int t = 0; t < nt; ++t) {
    const int s0 = t * 64;
    if (t + 1 < nt) {
      const size_t skn = (size_t)(s0 + 64) * 128;
#pragma unroll
      for (int c = 0; c < 4; ++c) gl_lds16(Kp + skn + koff[c], Kb[cur ^ 1] + dstc[c]);
#pragma unroll
      for (int c = 0; c < 4; ++c) gl_lds16(Vp + (s0 + 64) + voff[c], Vb[cur ^ 1] + dstc[c]);
    }
    if (s0 <= qw + 31) {
      const char* Kc = (const char*)Kb[cur];
      f32x4 sf[2][4];
      __builtin_amdgcn_s_setprio(1);
#pragma unroll
      for (int sj = 0; sj < 4; ++sj) {
        f32x4 a0 = zero, a1 = zero;
#pragma unroll
        for (int i = 0; i < 4; ++i) {
          bf16x8 kf = *(const bf16x8*)(Kc + ((((sj * 16 + lr) * 256) + (i * 32 + lk) * 2) ^ kxor));
          a0 = __builtin_amdgcn_mfma_f32_16x16x32_bf16(qf[0][i], kf, a0, 0, 0, 0);
          a1 = __builtin_amdgcn_mfma_f32_16x16x32_bf16(qf[1][i], kf, a1, 0, 0, 0);
        }
        sf[0][sj] = a0; sf[1][sj] = a1;
      }
      __builtin_amdgcn_s_setprio(0);

      char* Pc = (char*)Pl[w];
      const bool diag = (s0 + 63 > qw);             // wave-uniform: diagonal tile
      float pmax[2][4];
      bool need = false;
#pragma unroll
      for (int s = 0; s < 2; ++s)
#pragma unroll
        for (int r = 0; r < 4; ++r) {
          if (diag) {
            const int rq = qw + s * 16 + rbase + r;
#pragma unroll
            for (int sj = 0; sj < 4; ++sj)
              if (s0 + sj * 16 + lr > rq) sf[s][sj][r] = -1e30f;
          }
          float pm = fmaxf(fmaxf(sf[s][0][r], sf[s][1][r]),
                           fmaxf(sf[s][2][r], sf[s][3][r]));
          pmax[s][r] = pm;
          need |= (pm > mrow[s][r] + 8.f);
        }
      if (__any(need)) {                            // rare: full reduce + rescale
#pragma unroll
        for (int s = 0; s < 2; ++s)
#pragma unroll
          for (int r = 0; r < 4; ++r) {
            float pm = pmax[s][r];
            pm = fmaxf(pm, __shfl_xor(pm, 1));
            pm = fmaxf(pm, __shfl_xor(pm, 2));
            pm = fmaxf(pm, __shfl_xor(pm, 4));
            pm = fmaxf(pm, __shfl_xor(pm, 8));
            float mnew = fmaxf(mrow[s][r], pm);
            float sfac = __builtin_amdgcn_exp2f(mrow[s][r] - mnew);
            mrow[s][r] = mnew;
            lrow[s][r] *= sfac;
#pragma unroll
            for (int f = 0; f < 8; ++f) o[s][f][r] *= sfac;
          }
      }
      // P = exp2(S - m), per-lane partial sums, packed b64 store (sigma k-space)
#pragma unroll
      for (int s = 0; s < 2; ++s)
#pragma unroll
        for (int r = 0; r < 4; ++r) {
          const int prow = s * 16 + rbase + r;
          u16x4 pk;
          float ps = 0.f;
#pragma unroll
          for (int sj = 0; sj < 4; ++sj) {
            float p = __builtin_amdgcn_exp2f(sf[s][sj][r] - mrow[s][r]);
            ps += p;
            pk[sj] = f2b(p);
          }
          lrow[s][r] += ps;
          *(u16x4*)(Pc + ((prow * 128 + lr * 8) ^ ((prow & 7) << 4))) = pk;
        }

      const char* Vc = (const char*)Vb[cur];
      __builtin_amdgcn_s_setprio(1);
#pragma unroll
      for (int st = 0; st < 2; ++st) {
        bf16x8 pf0 = *(const bf16x8*)(Pc + (((lr * 128) + (st * 32 + lk) * 2) ^ kxor));
        bf16x8 pf1 = *(const bf16x8*)(Pc + ((((16 + lr) * 128) + (st * 32 + lk) * 2) ^ kxor));
#pragma unroll
        for (int f = 0; f < 8; ++f) {
          bf16x8 vf = *(const bf16x8*)(Vc + ((((f * 16 + lr) * 128) + (st * 32 + lk) * 2) ^ kxor));
          o[0][f] = __builtin_amdgcn_mfma_f32_16x16x32_bf16(pf0, vf, o[0][f], 0, 0, 0);
          o[1][f] = __builtin_amdgcn_mfma_f32_16x16x32_bf16(pf1, vf, o[1][f], 0, 0, 0);
        }
      }
      __builtin_amdgcn_s_setprio(0);
    }
    __syncthreads();
    cur ^= 1;
  }

  // epilogue: reduce per-lane row-sum partials once, then write
#pragma unroll
  for (int s = 0; s < 2; ++s)
#pragma unroll
    for (int r = 0; r < 4; ++r) {
      float l = lrow[s][r];
      l += __shfl_xor(l, 1);
      l += __shfl_xor(l, 2);
      l += __shfl_xor(l, 4);
      l += __shfl_xor(l, 8);
      const float rinv = __builtin_amdgcn_rcpf(l);
      const int row = qw + s * 16 + rbase + r;
#pragma unroll
      for (int f = 0; f < 8; ++f)
        y[((size_t)b * 2048 + row) * 2048 + h * 128 + f * 16 + lr] =
            f2b(o[s][f][r] * rinv);
    }
}

// ---------------- launch ----------------

extern "C" void kernel_launch(void* const* d_in, const int* in_sizes, int n_in,
                              void* d_out, int out_size, void* d_ws, size_t ws_size,
                              hipStream_t stream) {
  const float* x  = (const float*)d_in[0];
  const float* Wq = (const float*)d_in[1];
  const float* bq = (const float*)d_in[2];
  const float* Wk = (const float*)d_in[3];
  const float* bk = (const float*)d_in[4];
  const float* Wv = (const float*)d_in[5];
  const float* bv = (const float*)d_in[6];
  const float* Wo = (const float*)d_in[7];
  const float* bo = (const float*)d_in[8];
  float* out = (float*)d_out;
  char* ws = (char*)d_ws;

  u16* xb  = (u16*)(ws + 0);          // 16 MB; reused as yb after QKV GEMM
  u16* Wt  = (u16*)(ws + 16777216);   // 24 MB; front 8 MB reused as Wot, next 16 MB as vtb
  u16* qb  = (u16*)(ws + 41943040);   // 16 MB
  u16* kb  = (u16*)(ws + 58720256);   // 16 MB
  u16* vb  = (u16*)(ws + 75497472);   // 16 MB (total 88 MB)
  u16* Wot = Wt;                      // [2048][2048] bf16 = 8 MB
  u16* vtb = (u16*)(ws + 25165824);   // [B,H,128,T] bf16 = 16 MB
  u16* yb  = xb;

  cast_x_kernel<<<8192, 256, 0, stream>>>(x, xb, M_TOT * D_MODEL);
  trans_wqkv_kernel<<<dim3(32, 48), 256, 0, stream>>>(Wq, Wk, Wv, Wt);
  gemm256_kernel<0, 256><<<384, 512, 0, stream>>>(
      xb, Wt, qb, kb, vb, bq, bk, bv, nullptr, nullptr);
  trans_wo_kernel<<<dim3(32, 16), 256, 0, stream>>>(Wo, Wot);
  transpose_v_kernel<<<dim3(32, 32), 256, 0, stream>>>(vb, vtb);
  attn_kernel<<<512, 256, 0, stream>>>(qb, kb, vtb, yb);
  gemm256_kernel<1, 128><<<256, 512, 0, stream>>>(
      yb, Wot, nullptr, nullptr, nullptr, nullptr, nullptr, nullptr, out, bo);
}

// Round 7
// 298.037 us; speedup vs baseline: 1.0409x; 1.0409x over previous
//
#include <hip/hip_runtime.h>
#include <stdint.h>

typedef unsigned short u16;
typedef __attribute__((ext_vector_type(4))) u16 u16x4;
typedef __attribute__((ext_vector_type(8))) u16 u16x8;
typedef __attribute__((ext_vector_type(8))) __bf16 bf16x8;
typedef __attribute__((ext_vector_type(4))) float f32x4;

#define D_MODEL 2048
#define N_HEADS 16
#define HEAD_DIM 128
#define BATCH 2
#define SEQ 2048
#define M_TOT (BATCH*SEQ)          // 4096
#define N_QKV (3*D_MODEL)          // 6144

__device__ __forceinline__ u16 f2b(float f) {
  union { float f; uint32_t u; } c; c.f = f;
  uint32_t u = c.u;
  uint32_t r = (u + 0x7fffu + ((u >> 16) & 1u)) >> 16;
  return (u16)r;
}

__device__ __forceinline__ void gl_lds16(const u16* g, u16* l) {
  __builtin_amdgcn_global_load_lds(
      (const __attribute__((address_space(1))) uint32_t*)g,
      (__attribute__((address_space(3))) uint32_t*)l, 16, 0, 0);
}

template <int N> __device__ __forceinline__ void waitvm() {
  if constexpr (N == 5)      asm volatile("s_waitcnt vmcnt(5)" ::: "memory");
  else if constexpr (N == 4) asm volatile("s_waitcnt vmcnt(4)" ::: "memory");
  else if constexpr (N == 3) asm volatile("s_waitcnt vmcnt(3)" ::: "memory");
  else if constexpr (N == 2) asm volatile("s_waitcnt vmcnt(2)" ::: "memory");
  else                       asm volatile("s_waitcnt vmcnt(0)" ::: "memory");
}

// ---------------- prep kernels ----------------

__global__ void cast_x_kernel(const float* __restrict__ x, u16* __restrict__ xb, int n) {
  int i = (blockIdx.x * blockDim.x + threadIdx.x) * 4;
  if (i >= n) return;
  f32x4 v = *(const f32x4*)(x + i);
  u16x4 o;
  o[0] = f2b(v[0]); o[1] = f2b(v[1]); o[2] = f2b(v[2]); o[3] = f2b(v[3]);
  *(u16x4*)(xb + i) = o;
}

// Wq/Wk/Wv [H][2048][128] f32  ->  Wt [6144][2048] bf16, row n=(qkv*2048+h*128+d), K-major
__global__ void trans_wqkv_kernel(const float* __restrict__ Wq, const float* __restrict__ Wk,
                                  const float* __restrict__ Wv, u16* __restrict__ Wt) {
  __shared__ u16 Tl[128][72];
  const int hh = blockIdx.y;           // 0..47 = qkv*16+h
  const int qkv = hh >> 4, h = hh & 15;
  const float* src = (qkv == 0 ? Wq : qkv == 1 ? Wk : Wv) + (size_t)h * 2048 * 128;
  const int k0 = blockIdx.x * 64;
  const int tid = threadIdx.x;
  for (int it = 0; it < 32; ++it) {
    int idx = it * 256 + tid;
    int k = idx >> 7, d = idx & 127;
    Tl[d][k] = f2b(src[(size_t)(k0 + k) * 128 + d]);
  }
  __syncthreads();
  for (int it = 0; it < 32; ++it) {
    int idx = it * 256 + tid;
    int d = idx >> 6, kk = idx & 63;
    Wt[(size_t)(hh * 128 + d) * 2048 + k0 + kk] = Tl[d][kk];
  }
}

// Wo [2048][2048] f32 -> Wot [2048][2048] bf16 (transposed, K-major)
__global__ void trans_wo_kernel(const float* __restrict__ Wo, u16* __restrict__ Wot) {
  __shared__ u16 Tl[128][72];
  const int k0 = blockIdx.x * 64;     // 32 tiles
  const int n0 = blockIdx.y * 128;    // 16 tiles
  const int tid = threadIdx.x;
  for (int it = 0; it < 32; ++it) {
    int idx = it * 256 + tid;
    int k = idx >> 7, n = idx & 127;
    Tl[n][k] = f2b(Wo[(size_t)(k0 + k) * 2048 + n0 + n]);
  }
  __syncthreads();
  for (int it = 0; it < 32; ++it) {
    int idx = it * 256 + tid;
    int d = idx >> 6, kk = idx & 63;
    Wot[(size_t)(n0 + d) * 2048 + k0 + kk] = Tl[d][kk];
  }
}

// vb [B,H,T,128] bf16 -> vt [B,H,128,T] bf16 with sigma-permuted columns within
// each 64-tile: sigma(t) = (t&15)*4 + (t>>4). Matches attn's packed-P k-space.
__global__ void transpose_v_kernel(const u16* __restrict__ vb, u16* __restrict__ vt) {
  __shared__ u16 Tl[128 * 65];
  const int bh = blockIdx.y;
  const int t0 = blockIdx.x * 64;
  const int tid = threadIdx.x;
  const u16* src = vb + (size_t)bh * 2048 * 128;
  u16* dstp = vt + (size_t)bh * 128 * 2048;
#pragma unroll
  for (int c = 0; c < 4; ++c) {
    int ci = c * 256 + tid;
    int tr = ci >> 4, d0 = (ci & 15) * 8;
    u16x8 v = *(const u16x8*)(src + (size_t)(t0 + tr) * 128 + d0);
#pragma unroll
    for (int e = 0; e < 8; ++e) Tl[(d0 + e) * 65 + tr] = v[e];
  }
  __syncthreads();
#pragma unroll
  for (int it = 0; it < 32; ++it) {
    int idx = it * 256 + tid;
    int d = idx >> 6, tt = idx & 63;
    dstp[(size_t)d * 2048 + t0 + ((tt & 15) * 4 + (tt >> 4))] = Tl[d * 65 + tt];
  }
}

// ---------- GEMM: 128xBN tile, BK=64, 4-phase quadrant schedule, counted vmcnt ----------
// 512 threads = 8 waves (2M x 4N); wave tile 64 x BNW (BNW = BN/4).
// Per K-tile 4 phases, each = one C-quadrant (ah,hb) with full k=64:
//   P0{ds A0+B0 | stage A'+Bq0' | 12*mfma | vmcnt(NBQ+2)}  P1{ds B1 | stage Bq1' | mfma}
//   P2{ds A1 | mfma}  P3{mfma | vmcnt(NBQ)}   (vmcnt never 0 except peeled last tile)
// LDS dbuf=2: A[2][128][64], B[2][BN][64] bf16, 128-B rows, XOR-swizzle
// byte ^= (row&7)<<4 with pre-swizzled global source (linear gl_lds dest).
// B staged in consumption-aligned stripe-halves: half hb covers rows
// {s*BNW + hb*SW + [0,SW)} for s=0..3 (exactly the rows phase (·,hb) reads).
template <int EPI, int BN>
__global__ __launch_bounds__(512, 2) void gemm4p_kernel(
    const u16* __restrict__ A, const u16* __restrict__ B,
    u16* __restrict__ qo, u16* __restrict__ ko, u16* __restrict__ vo,
    const float* __restrict__ bq, const float* __restrict__ bk, const float* __restrict__ bv,
    float* __restrict__ outf, const float* __restrict__ bo) {
  constexpr int BNW = BN / 4, SW = BNW / 2, NBF = SW / 16;   // 96,48,3 | 64,32,2
  constexpr int NBQ = NBF;                                   // B loads/thread per half
  constexpr int ASZ = 128 * 64, BSZ = BN * 64;               // u16 per slot
  __shared__ u16 HA[2 * ASZ];
  __shared__ u16 HB[2 * BSZ];
  constexpr int NXT = (EPI == 0) ? (6144 / BN) : (2048 / BN);
  const int nwg = gridDim.x, q8 = nwg >> 3, bid0 = blockIdx.x;
  const int gid = (bid0 & 7) * q8 + (bid0 >> 3);   // XCD-chunked, bijective
  const int m0 = (gid / NXT) * 128, n0 = (gid % NXT) * BN;

  const int tid = threadIdx.x, lane = tid & 63, w = tid >> 6;
  const int wm = (w >> 2) * 64, wn = (w & 3) * BNW;
  const int lr = lane & 15, lk = (lane >> 4) * 8;
  const int kb0 = lk * 2;                 // byte col of k-chunk 0
  const int rx = (lr & 7) << 4;           // read-side XOR
  const int ws4 = (w & 3) * SW;           // wave's stripe base (rows within stripe-group)

  // stage address precompute (source pre-swizzled: chunk j -> j ^ (row&7))
  int aoff[2], boff[2][NBQ];
#pragma unroll
  for (int l = 0; l < 2; ++l) {
    int ci = l * 512 + tid, row = ci >> 3, j = ci & 7;
    aoff[l] = (m0 + row) * 2048 + (j ^ (row & 7)) * 8;
  }
#pragma unroll
  for (int hb = 0; hb < 2; ++hb)
#pragma unroll
    for (int l = 0; l < NBQ; ++l) {
      int cj = l * 512 + tid;
      int s = cj / (SW * 8), rem = cj % (SW * 8);
      int r = rem >> 3, j = rem & 7;
      int row = s * BNW + hb * SW + r;
      boff[hb][l] = (n0 + row) * 2048 + (j ^ (row & 7)) * 8;
    }
  const int dst0 = tid * 8;               // linear u16 chunk offset

  f32x4 acc[2][2][2][NBF];
  const f32x4 zero = {0.f, 0.f, 0.f, 0.f};
#pragma unroll
  for (int ah = 0; ah < 2; ++ah)
#pragma unroll
    for (int ai = 0; ai < 2; ++ai)
#pragma unroll
      for (int hb = 0; hb < 2; ++hb)
#pragma unroll
        for (int bj = 0; bj < NBF; ++bj) acc[ah][ai][hb][bj] = zero;

  bf16x8 af[2][2][2], bfr[2][NBF][2];

#define READ_A(AH, ACB)                                                              \
  _Pragma("unroll") for (int ai = 0; ai < 2; ++ai) {                                 \
    int row = wm + (AH) * 32 + ai * 16 + lr;                                         \
    _Pragma("unroll") for (int kk = 0; kk < 2; ++kk)                                 \
      af[AH][ai][kk] = *(const bf16x8*)((ACB) + row * 128 + ((kb0 + kk * 64) ^ rx)); \
  }
#define READ_B(HB, BCB)                                                              \
  _Pragma("unroll") for (int bj = 0; bj < NBF; ++bj) {                               \
    int row = ((HB) * 4) * SW + ws4 + bj * 16 + lr;                                  \
    _Pragma("unroll") for (int kk = 0; kk < 2; ++kk)                                 \
      bfr[HB][bj][kk] = *(const bf16x8*)((BCB) + row * 128 + ((kb0 + kk * 64) ^ rx));\
  }
#define MMA(AH, HB)                                                                  \
  __builtin_amdgcn_s_setprio(1);                                                     \
  _Pragma("unroll") for (int ai = 0; ai < 2; ++ai)                                   \
    _Pragma("unroll") for (int bj = 0; bj < NBF; ++bj)                               \
      _Pragma("unroll") for (int kk = 0; kk < 2; ++kk)                               \
        acc[AH][ai][HB][bj] = __builtin_amdgcn_mfma_f32_16x16x32_bf16(               \
            af[AH][ai][kk], bfr[HB][bj][kk], acc[AH][ai][HB][bj], 0, 0, 0);          \
  __builtin_amdgcn_s_setprio(0);
#define BAR __builtin_amdgcn_s_barrier()
#define LGKM0 asm volatile("s_waitcnt lgkmcnt(0)" ::: "memory")

  // prologue: stage tile 0 into slot 0, drain, barrier
#pragma unroll
  for (int l = 0; l < 2; ++l) gl_lds16(A + aoff[l], HA + l * 4096 + dst0);
#pragma unroll
  for (int hb = 0; hb < 2; ++hb)
#pragma unroll
    for (int l = 0; l < NBQ; ++l)
      gl_lds16(B + boff[hb][l], HB + hb * (BSZ / 2) + l * 4096 + dst0);
  waitvm<0>();
  BAR;

  for (int kt = 0; kt < 31; ++kt) {
    const int c = kt & 1, ns = c ^ 1;
    const char* Acb = (const char*)(HA + c * ASZ);
    const char* Bcb = (const char*)(HB + c * BSZ);
    const int k2 = (kt + 1) * 64;
    // P0: quadrant (0,0); stage A' + Bq0'
    READ_A(0, Acb); READ_B(0, Bcb);
#pragma unroll
    for (int l = 0; l < 2; ++l) gl_lds16(A + aoff[l] + k2, HA + ns * ASZ + l * 4096 + dst0);
#pragma unroll
    for (int l = 0; l < NBQ; ++l)
      gl_lds16(B + boff[0][l] + k2, HB + ns * BSZ + l * 4096 + dst0);
    BAR; LGKM0;
    MMA(0, 0);
    waitvm<NBQ + 2>();
    BAR;
    // P1: quadrant (0,1); stage Bq1'
    READ_B(1, Bcb);
#pragma unroll
    for (int l = 0; l < NBQ; ++l)
      gl_lds16(B + boff[1][l] + k2, HB + ns * BSZ + (BSZ / 2) + l * 4096 + dst0);
    BAR; LGKM0;
    MMA(0, 1);
    BAR;
    // P2: quadrant (1,1)
    READ_A(1, Acb);
    BAR; LGKM0;
    MMA(1, 1);
    BAR;
    // P3: quadrant (1,0)
    MMA(1, 0);
    waitvm<NBQ>();
    BAR;
  }
  // peeled kt = 31 (slot 1), no staging
  {
    const char* Acb = (const char*)(HA + ASZ);
    const char* Bcb = (const char*)(HB + BSZ);
    READ_A(0, Acb); READ_B(0, Bcb);
    BAR; LGKM0;
    MMA(0, 0);
    waitvm<0>();
    BAR;
    READ_B(1, Bcb);
    BAR; LGKM0;
    MMA(0, 1);
    BAR;
    READ_A(1, Acb);
    BAR; LGKM0;
    MMA(1, 1);
    MMA(1, 0);
  }
#undef READ_A
#undef READ_B
#undef MMA
#undef BAR
#undef LGKM0

  const int rbase = (lane >> 4) * 4;
  if (EPI == 0) {
    const float qscale = 0.08838834764831845f * 1.4426950408889634f;  // 1/sqrt(128)*log2e
#pragma unroll
    for (int hb = 0; hb < 2; ++hb)
#pragma unroll
      for (int bj = 0; bj < NBF; ++bj) {
        const int n = n0 + wn + hb * SW + bj * 16 + lr;
        const int qkv = n >> 11, hh = (n >> 7) & 15, d = n & 127;
        const float* bias = (qkv == 0) ? bq : (qkv == 1) ? bk : bv;
        u16* dst = (qkv == 0) ? qo : (qkv == 1) ? ko : vo;
        const float bv_ = bias[n & 2047];
#pragma unroll
        for (int ah = 0; ah < 2; ++ah)
#pragma unroll
          for (int ai = 0; ai < 2; ++ai)
#pragma unroll
            for (int r = 0; r < 4; ++r) {
              int gm = m0 + wm + ah * 32 + ai * 16 + rbase + r;
              float val = acc[ah][ai][hb][bj][r] + bv_;
              if (qkv == 0) val *= qscale;
              int b = gm >> 11, t = gm & 2047;
              dst[((size_t)(b * 16 + hh) * 2048 + t) * 128 + d] = f2b(val);
            }
      }
  } else {
#pragma unroll
    for (int hb = 0; hb < 2; ++hb)
#pragma unroll
      for (int bj = 0; bj < NBF; ++bj) {
        const int gn = n0 + wn + hb * SW + bj * 16 + lr;
        const float bv_ = bo[gn];
#pragma unroll
        for (int ah = 0; ah < 2; ++ah)
#pragma unroll
          for (int ai = 0; ai < 2; ++ai)
#pragma unroll
            for (int r = 0; r < 4; ++r) {
              int gm = m0 + wm + ah * 32 + ai * 16 + rbase + r;
              outf[(size_t)gm * 2048 + gn] = acc[ah][ai][hb][bj][r] + bv_;
            }
      }
  }
}

// ---------------- flash attention (causal) ----------------
// 512 blocks of 256 threads; bid -> bh = bid&31 (XCD-grouped), qt = 15-(bid>>5)
// (heaviest blocks dispatch first; 2 blocks/CU co-resident at 80KB LDS).
// 4 waves x 32 q-rows; KV tile 64, double-buffered, gl_lds staging pre-swizzled.
// Softmax: per-lane partial row-sums (reduced once at end), defer-max with
// lane-local check (no per-tile shuffles on common path), packed b64 P stores
// in sigma-permuted k-space matching the sigma-permuted V^T.
// Q arrives pre-scaled by 1/sqrt(128)*log2e -> scores in exp2 domain.
__global__ __launch_bounds__(256) void attn_kernel(
    const u16* __restrict__ qg, const u16* __restrict__ kg,
    const u16* __restrict__ vtg, u16* __restrict__ y) {
  __shared__ u16 Kb[2][64 * 128];
  __shared__ u16 Vb[2][128 * 64];
  __shared__ u16 Pl[4][32 * 64];
  const int tid = threadIdx.x, lane = tid & 63, w = tid >> 6;
  const int bid = blockIdx.x;
  const int bh = bid & 31, qt = 15 - (bid >> 5);
  const int b = bh >> 4, h = bh & 15;
  const int lr = lane & 15, lk = (lane >> 4) * 8;
  const u16* Qp = qg + (size_t)bh * (2048 * 128);
  const u16* Kp = kg + (size_t)bh * (2048 * 128);
  const u16* Vp = vtg + (size_t)bh * (128 * 2048);

  int koff[4], voff[4], dstc[4];
#pragma unroll
  for (int c = 0; c < 4; ++c) {
    int ci = c * 256 + tid;
    dstc[c] = ci * 8;
    int kr = ci >> 4, kj = ci & 15;                 // K tile: 64 rows x 16 chunks
    koff[c] = kr * 128 + (kj ^ (kr & 7)) * 8;
    int vd = ci >> 3, vj = ci & 7;                  // V^T tile: 128 rows x 8 chunks
    voff[c] = vd * 2048 + (vj ^ (vd & 7)) * 8;
  }
  const int kxor = (lr & 7) << 4;
  const int rbase = (lane >> 4) * 4;
  const f32x4 zero = {0.f, 0.f, 0.f, 0.f};

  const int q0 = qt * 128;
  const int qw = q0 + w * 32;
  const int nt = 2 * qt + 2;

  bf16x8 qf[2][4];
#pragma unroll
  for (int s = 0; s < 2; ++s)
#pragma unroll
    for (int i = 0; i < 4; ++i)
      qf[s][i] = *(const bf16x8*)(Qp + (size_t)(qw + s * 16 + lr) * 128 + i * 32 + lk);

  f32x4 o[2][8];
#pragma unroll
  for (int s = 0; s < 2; ++s)
#pragma unroll
    for (int f = 0; f < 8; ++f) o[s][f] = zero;
  float mrow[2][4], lrow[2][4];
#pragma unroll
  for (int s = 0; s < 2; ++s)
#pragma unroll
    for (int r = 0; r < 4; ++r) { mrow[s][r] = -1e30f; lrow[s][r] = 0.f; }

  // prologue: stage tile 0
#pragma unroll
  for (int c = 0; c < 4; ++c) gl_lds16(Kp + koff[c], Kb[0] + dstc[c]);
#pragma unroll
  for (int c = 0; c < 4; ++c) gl_lds16(Vp + voff[c], Vb[0] + dstc[c]);
  __syncthreads();

  int cur = 0;
  for (int t = 0; t < nt; ++t) {
    const int s0 = t * 64;
    if (t + 1 < nt) {
      const size_t skn = (size_t)(s0 + 64) * 128;
#pragma unroll
      for (int c = 0; c < 4; ++c) gl_lds16(Kp + skn + koff[c], Kb[cur ^ 1] + dstc[c]);
#pragma unroll
      for (int c = 0; c < 4; ++c) gl_lds16(Vp + (s0 + 64) + voff[c], Vb[cur ^ 1] + dstc[c]);
    }
    if (s0 <= qw + 31) {
      const char* Kc = (const char*)Kb[cur];
      f32x4 sf[2][4];
      __builtin_amdgcn_s_setprio(1);
#pragma unroll
      for (int sj = 0; sj < 4; ++sj) {
        f32x4 a0 = zero, a1 = zero;
#pragma unroll
        for (int i = 0; i < 4; ++i) {
          bf16x8 kf = *(const bf16x8*)(Kc + ((((sj * 16 + lr) * 256) + (i * 32 + lk) * 2) ^ kxor));
          a0 = __builtin_amdgcn_mfma_f32_16x16x32_bf16(qf[0][i], kf, a0, 0, 0, 0);
          a1 = __builtin_amdgcn_mfma_f32_16x16x32_bf16(qf[1][i], kf, a1, 0, 0, 0);
        }
        sf[0][sj] = a0; sf[1][sj] = a1;
      }
      __builtin_amdgcn_s_setprio(0);

      char* Pc = (char*)Pl[w];
      const bool diag = (s0 + 63 > qw);             // wave-uniform: diagonal tile
      float pmax[2][4];
      bool need = false;
#pragma unroll
      for (int s = 0; s < 2; ++s)
#pragma unroll
        for (int r = 0; r < 4; ++r) {
          if (diag) {
            const int rq = qw + s * 16 + rbase + r;
#pragma unroll
            for (int sj = 0; sj < 4; ++sj)
              if (s0 + sj * 16 + lr > rq) sf[s][sj][r] = -1e30f;
          }
          float pm = fmaxf(fmaxf(sf[s][0][r], sf[s][1][r]),
                           fmaxf(sf[s][2][r], sf[s][3][r]));
          pmax[s][r] = pm;
          need |= (pm > mrow[s][r] + 8.f);
        }
      if (__any(need)) {                            // rare: full reduce + rescale
#pragma unroll
        for (int s = 0; s < 2; ++s)
#pragma unroll
          for (int r = 0; r < 4; ++r) {
            float pm = pmax[s][r];
            pm = fmaxf(pm, __shfl_xor(pm, 1));
            pm = fmaxf(pm, __shfl_xor(pm, 2));
            pm = fmaxf(pm, __shfl_xor(pm, 4));
            pm = fmaxf(pm, __shfl_xor(pm, 8));
            float mnew = fmaxf(mrow[s][r], pm);
            float sfac = __builtin_amdgcn_exp2f(mrow[s][r] - mnew);
            mrow[s][r] = mnew;
            lrow[s][r] *= sfac;
#pragma unroll
            for (int f = 0; f < 8; ++f) o[s][f][r] *= sfac;
          }
      }
      // P = exp2(S - m), per-lane partial sums, packed b64 store (sigma k-space)
#pragma unroll
      for (int s = 0; s < 2; ++s)
#pragma unroll
        for (int r = 0; r < 4; ++r) {
          const int prow = s * 16 + rbase + r;
          u16x4 pk;
          float ps = 0.f;
#pragma unroll
          for (int sj = 0; sj < 4; ++sj) {
            float p = __builtin_amdgcn_exp2f(sf[s][sj][r] - mrow[s][r]);
            ps += p;
            pk[sj] = f2b(p);
          }
          lrow[s][r] += ps;
          *(u16x4*)(Pc + ((prow * 128 + lr * 8) ^ ((prow & 7) << 4))) = pk;
        }

      const char* Vc = (const char*)Vb[cur];
      __builtin_amdgcn_s_setprio(1);
#pragma unroll
      for (int st = 0; st < 2; ++st) {
        bf16x8 pf0 = *(const bf16x8*)(Pc + (((lr * 128) + (st * 32 + lk) * 2) ^ kxor));
        bf16x8 pf1 = *(const bf16x8*)(Pc + ((((16 + lr) * 128) + (st * 32 + lk) * 2) ^ kxor));
#pragma unroll
        for (int f = 0; f < 8; ++f) {
          bf16x8 vf = *(const bf16x8*)(Vc + ((((f * 16 + lr) * 128) + (st * 32 + lk) * 2) ^ kxor));
          o[0][f] = __builtin_amdgcn_mfma_f32_16x16x32_bf16(pf0, vf, o[0][f], 0, 0, 0);
          o[1][f] = __builtin_amdgcn_mfma_f32_16x16x32_bf16(pf1, vf, o[1][f], 0, 0, 0);
        }
      }
      __builtin_amdgcn_s_setprio(0);
    }
    __syncthreads();
    cur ^= 1;
  }

  // epilogue: reduce per-lane row-sum partials once, then write
#pragma unroll
  for (int s = 0; s < 2; ++s)
#pragma unroll
    for (int r = 0; r < 4; ++r) {
      float l = lrow[s][r];
      l += __shfl_xor(l, 1);
      l += __shfl_xor(l, 2);
      l += __shfl_xor(l, 4);
      l += __shfl_xor(l, 8);
      const float rinv = __builtin_amdgcn_rcpf(l);
      const int row = qw + s * 16 + rbase + r;
#pragma unroll
      for (int f = 0; f < 8; ++f)
        y[((size_t)b * 2048 + row) * 2048 + h * 128 + f * 16 + lr] =
            f2b(o[s][f][r] * rinv);
    }
}

// ---------------- launch ----------------

extern "C" void kernel_launch(void* const* d_in, const int* in_sizes, int n_in,
                              void* d_out, int out_size, void* d_ws, size_t ws_size,
                              hipStream_t stream) {
  const float* x  = (const float*)d_in[0];
  const float* Wq = (const float*)d_in[1];
  const float* bq = (const float*)d_in[2];
  const float* Wk = (const float*)d_in[3];
  const float* bk = (const float*)d_in[4];
  const float* Wv = (const float*)d_in[5];
  const float* bv = (const float*)d_in[6];
  const float* Wo = (const float*)d_in[7];
  const float* bo = (const float*)d_in[8];
  float* out = (float*)d_out;
  char* ws = (char*)d_ws;

  u16* xb  = (u16*)(ws + 0);          // 16 MB; reused as yb after QKV GEMM
  u16* Wt  = (u16*)(ws + 16777216);   // 24 MB; front 8 MB reused as Wot, next 16 MB as vtb
  u16* qb  = (u16*)(ws + 41943040);   // 16 MB
  u16* kb  = (u16*)(ws + 58720256);   // 16 MB
  u16* vb  = (u16*)(ws + 75497472);   // 16 MB (total 88 MB)
  u16* Wot = Wt;                      // [2048][2048] bf16 = 8 MB
  u16* vtb = (u16*)(ws + 25165824);   // [B,H,128,T] bf16 = 16 MB
  u16* yb  = xb;

  cast_x_kernel<<<8192, 256, 0, stream>>>(x, xb, M_TOT * D_MODEL);
  trans_wqkv_kernel<<<dim3(32, 48), 256, 0, stream>>>(Wq, Wk, Wv, Wt);
  gemm4p_kernel<0, 384><<<512, 512, 0, stream>>>(
      xb, Wt, qb, kb, vb, bq, bk, bv, nullptr, nullptr);
  trans_wo_kernel<<<dim3(32, 16), 256, 0, stream>>>(Wo, Wot);
  transpose_v_kernel<<<dim3(32, 32), 256, 0, stream>>>(vb, vtb);
  attn_kernel<<<512, 256, 0, stream>>>(qb, kb, vtb, yb);
  gemm4p_kernel<1, 256><<<256, 512, 0, stream>>>(
      yb, Wot, nullptr, nullptr, nullptr, nullptr, nullptr, nullptr, out, bo);
}

// Round 9
// 282.946 us; speedup vs baseline: 1.0964x; 1.0533x over previous
//
#include <hip/hip_runtime.h>
#include <stdint.h>

typedef unsigned short u16;
typedef __attribute__((ext_vector_type(4))) u16 u16x4;
typedef __attribute__((ext_vector_type(8))) u16 u16x8;
typedef __attribute__((ext_vector_type(8))) __bf16 bf16x8;
typedef __attribute__((ext_vector_type(4))) float f32x4;
typedef __attribute__((ext_vector_type(16))) float f32x16;

#define D_MODEL 2048
#define N_HEADS 16
#define HEAD_DIM 128
#define BATCH 2
#define SEQ 2048
#define M_TOT (BATCH*SEQ)          // 4096
#define N_QKV (3*D_MODEL)          // 6144

__device__ __forceinline__ u16 f2b(float f) {
  union { float f; uint32_t u; } c; c.f = f;
  uint32_t u = c.u;
  uint32_t r = (u + 0x7fffu + ((u >> 16) & 1u)) >> 16;
  return (u16)r;
}

__device__ __forceinline__ void gl_lds16(const u16* g, u16* l) {
  __builtin_amdgcn_global_load_lds(
      (const __attribute__((address_space(1))) uint32_t*)g,
      (__attribute__((address_space(3))) uint32_t*)l, 16, 0, 0);
}

template <int N> __device__ __forceinline__ void waitvm() {
  if constexpr (N == 6)      asm volatile("s_waitcnt vmcnt(6)" ::: "memory");
  else if constexpr (N == 5) asm volatile("s_waitcnt vmcnt(5)" ::: "memory");
  else                       asm volatile("s_waitcnt vmcnt(0)" ::: "memory");
}

// ---------------- prep kernels ----------------

__global__ void cast_x_kernel(const float* __restrict__ x, u16* __restrict__ xb, int n) {
  int i = (blockIdx.x * blockDim.x + threadIdx.x) * 4;
  if (i >= n) return;
  f32x4 v = *(const f32x4*)(x + i);
  u16x4 o;
  o[0] = f2b(v[0]); o[1] = f2b(v[1]); o[2] = f2b(v[2]); o[3] = f2b(v[3]);
  *(u16x4*)(xb + i) = o;
}

// Wq/Wk/Wv [H][2048][128] f32  ->  Wt [6144][2048] bf16, row n=(qkv*2048+h*128+d), K-major
__global__ void trans_wqkv_kernel(const float* __restrict__ Wq, const float* __restrict__ Wk,
                                  const float* __restrict__ Wv, u16* __restrict__ Wt) {
  __shared__ u16 Tl[128][72];
  const int hh = blockIdx.y;           // 0..47 = qkv*16+h
  const int qkv = hh >> 4, h = hh & 15;
  const float* src = (qkv == 0 ? Wq : qkv == 1 ? Wk : Wv) + (size_t)h * 2048 * 128;
  const int k0 = blockIdx.x * 64;
  const int tid = threadIdx.x;
  for (int it = 0; it < 32; ++it) {
    int idx = it * 256 + tid;
    int k = idx >> 7, d = idx & 127;
    Tl[d][k] = f2b(src[(size_t)(k0 + k) * 128 + d]);
  }
  __syncthreads();
  for (int it = 0; it < 32; ++it) {
    int idx = it * 256 + tid;
    int d = idx >> 6, kk = idx & 63;
    Wt[(size_t)(hh * 128 + d) * 2048 + k0 + kk] = Tl[d][kk];
  }
}

// Wo [2048][2048] f32 -> Wot [2048][2048] bf16 (transposed, K-major)
__global__ void trans_wo_kernel(const float* __restrict__ Wo, u16* __restrict__ Wot) {
  __shared__ u16 Tl[128][72];
  const int k0 = blockIdx.x * 64;     // 32 tiles
  const int n0 = blockIdx.y * 128;    // 16 tiles
  const int tid = threadIdx.x;
  for (int it = 0; it < 32; ++it) {
    int idx = it * 256 + tid;
    int k = idx >> 7, n = idx & 127;
    Tl[n][k] = f2b(Wo[(size_t)(k0 + k) * 2048 + n0 + n]);
  }
  __syncthreads();
  for (int it = 0; it < 32; ++it) {
    int idx = it * 256 + tid;
    int d = idx >> 6, kk = idx & 63;
    Wot[(size_t)(n0 + d) * 2048 + k0 + kk] = Tl[d][kk];
  }
}

// vb [B,H,T,128] bf16 -> vt [B,H,128,T] bf16 with sigma-permuted columns within
// each 64-tile: sigma(t) = (t&15)*4 + (t>>4). Matches attn's packed-P k-space.
__global__ void transpose_v_kernel(const u16* __restrict__ vb, u16* __restrict__ vt) {
  __shared__ u16 Tl[128 * 65];
  const int bh = blockIdx.y;
  const int t0 = blockIdx.x * 64;
  const int tid = threadIdx.x;
  const u16* src = vb + (size_t)bh * 2048 * 128;
  u16* dstp = vt + (size_t)bh * 128 * 2048;
#pragma unroll
  for (int c = 0; c < 4; ++c) {
    int ci = c * 256 + tid;
    int tr = ci >> 4, d0 = (ci & 15) * 8;
    u16x8 v = *(const u16x8*)(src + (size_t)(t0 + tr) * 128 + d0);
#pragma unroll
    for (int e = 0; e < 8; ++e) Tl[(d0 + e) * 65 + tr] = v[e];
  }
  __syncthreads();
#pragma unroll
  for (int it = 0; it < 32; ++it) {
    int idx = it * 256 + tid;
    int d = idx >> 6, tt = idx & 63;
    dstp[(size_t)d * 2048 + t0 + ((tt & 15) * 4 + (tt >> 4))] = Tl[d * 65 + tt];
  }
}

// ---------- QKV GEMM: 256x384 tile, 32x32x16 MFMA, BK=32, ring-3, counted vmcnt ----------
// 512 thr = 8 waves (2M x 4N), wave tile 128x96 = 4x3 32x32 fragments (acc 192 f32/lane).
// LDS: 3 ring slots of {A[256][32], B[384][32]} bf16 (40 KB each, 120 KB total).
// Staging dests are tid*8-linear (wave-uniform base + lane*16 -- rule-21 safe);
// swizzle: granule j stored at j ^ ((row>>1)&3), pre-applied to the global source.
// Tile kt reads slot kt%3 and stages tile kt+2 (5 gl_lds/thread); end-of-tile
// s_waitcnt vmcnt(5) -> tile kt+1 landed, kt+2 in flight. Never 0 until drain.
__global__ __launch_bounds__(512, 2) void gemm_qkv_kernel(
    const u16* __restrict__ A, const u16* __restrict__ B,
    u16* __restrict__ qo, u16* __restrict__ ko, u16* __restrict__ vo,
    const float* __restrict__ bq, const float* __restrict__ bk, const float* __restrict__ bv) {
  __shared__ u16 LS[3][20480];   // A: [0,8192) u16, B: [8192,20480)
  const int bid0 = blockIdx.x;
  const int gid = (bid0 & 7) * 32 + (bid0 >> 3);   // XCD-chunked (256 blocks)
  const int G = gid >> 4, l = gid & 15;            // 16 groups of 4mt x 4nt
  const int m0 = ((G & 3) * 4 + (l & 3)) * 256;
  const int n0 = ((G >> 2) * 4 + (l >> 2)) * 384;

  const int tid = threadIdx.x, lane = tid & 63, w = tid >> 6;
  const int wm = (w >> 2) * 128, wn = (w & 3) * 96;
  const int l31 = lane & 31, g2 = lane >> 5;
  const int kx = ((l31 >> 1) & 3) << 4;            // read-side XOR (bytes)

  // staging: A 2 loads + B 3 loads per tile (16 B each)
  int aoff[2], boff[3];
#pragma unroll
  for (int l2 = 0; l2 < 2; ++l2) {
    int ci = l2 * 512 + tid, r = ci >> 2, j = ci & 3;
    aoff[l2] = (m0 + r) * 2048 + (j ^ ((r >> 1) & 3)) * 8;
  }
#pragma unroll
  for (int l2 = 0; l2 < 3; ++l2) {
    int ci = l2 * 512 + tid, r = ci >> 2, j = ci & 3;
    boff[l2] = (n0 + r) * 2048 + (j ^ ((r >> 1) & 3)) * 8;
  }
  const int adl = tid * 8;
  const int bdl = 8192 + tid * 8;

  f32x16 acc[4][3];
#pragma unroll
  for (int ai = 0; ai < 4; ++ai)
#pragma unroll
    for (int bj = 0; bj < 3; ++bj)
#pragma unroll
      for (int e = 0; e < 16; ++e) acc[ai][bj][e] = 0.f;

  // prologue: stage tiles 0,1 into slots 0,1
#pragma unroll
  for (int t = 0; t < 2; ++t) {
#pragma unroll
    for (int l2 = 0; l2 < 2; ++l2) gl_lds16(A + aoff[l2] + t * 32, LS[t] + adl + l2 * 4096);
#pragma unroll
    for (int l2 = 0; l2 < 3; ++l2) gl_lds16(B + boff[l2] + t * 32, LS[t] + bdl + l2 * 4096);
  }
  waitvm<5>();
  __builtin_amdgcn_s_barrier();

  int s = 0;
  for (int kt = 0; kt < 64; ++kt) {
    if (kt < 62) {
      const int s2 = (s == 0) ? 2 : s - 1;
      const int k2 = (kt + 2) * 32;
#pragma unroll
      for (int l2 = 0; l2 < 2; ++l2) gl_lds16(A + aoff[l2] + k2, LS[s2] + adl + l2 * 4096);
#pragma unroll
      for (int l2 = 0; l2 < 3; ++l2) gl_lds16(B + boff[l2] + k2, LS[s2] + bdl + l2 * 4096);
    }
    const char* base = (const char*)LS[s];
#pragma unroll
    for (int kk = 0; kk < 2; ++kk) {
      bf16x8 af[4];
#pragma unroll
      for (int ai = 0; ai < 4; ++ai) {
        int r = wm + ai * 32 + l31;
        af[ai] = *(const bf16x8*)(base + r * 64 + ((32 * kk + 16 * g2) ^ kx));
      }
      __builtin_amdgcn_s_setprio(1);
#pragma unroll
      for (int bj = 0; bj < 3; ++bj) {
        int rb = wn + bj * 32 + l31;
        bf16x8 bfr = *(const bf16x8*)(base + 16384 + rb * 64 + ((32 * kk + 16 * g2) ^ kx));
#pragma unroll
        for (int ai = 0; ai < 4; ++ai)
          acc[ai][bj] = __builtin_amdgcn_mfma_f32_32x32x16_bf16(af[ai], bfr, acc[ai][bj], 0, 0, 0);
      }
      __builtin_amdgcn_s_setprio(0);
    }
    if (kt < 62)       waitvm<5>();
    else if (kt == 62) waitvm<0>();
    __builtin_amdgcn_s_barrier();
    s = (s == 2) ? 0 : s + 1;
  }

  // epilogue: C/D 32x32 layout col=lane&31, row=(reg&3)+8*(reg>>2)+4*(lane>>5)
  const float qscale = 0.08838834764831845f * 1.4426950408889634f;  // 1/sqrt(128)*log2e
#pragma unroll
  for (int bj = 0; bj < 3; ++bj) {
    const int n = n0 + wn + bj * 32 + l31;
    const int qkv = n >> 11, hh = (n >> 7) & 15, d = n & 127;
    const float* bias = (qkv == 0) ? bq : (qkv == 1) ? bk : bv;
    u16* dst = (qkv == 0) ? qo : (qkv == 1) ? ko : vo;
    const float bv_ = bias[n & 2047];
#pragma unroll
    for (int ai = 0; ai < 4; ++ai)
#pragma unroll
      for (int e = 0; e < 16; ++e) {
        int row = (e & 3) + 8 * (e >> 2) + 4 * g2;
        int gm = m0 + wm + ai * 32 + row;
        float val = acc[ai][bj][e] + bv_;
        if (qkv == 0) val *= qscale;
        int b = gm >> 11, t = gm & 2047;
        dst[((size_t)(b * 16 + hh) * 2048 + t) * 128 + d] = f2b(val);
      }
  }
}

// ---------- Output GEMM: 256x128 tile, 16x16x32 MFMA, BK=64, ring-3, counted vmcnt ----------
// 512 thr = 8 waves (4M x 2N), wave 64x64 = 4x4 16x16 frags (acc 64 f32/lane).
// LDS: 3 ring slots of {A[256][64], B[128][64]} bf16 (48 KB each, 144 KB).
// Staging dests tid*8-linear (rule-21 safe); source pre-swizzled with full
// granule XOR gj ^ (row&7) within the 8-granule 128-B row (0-conflict reads).
// Tile kt reads slot kt%3, stages kt+2 (6 loads/thread); vmcnt(6) per tile.
__global__ __launch_bounds__(512, 2) void gemm_out_kernel(
    const u16* __restrict__ A, const u16* __restrict__ B,
    float* __restrict__ outf, const float* __restrict__ bo) {
  __shared__ u16 LS[3][24576];   // A: [0,16384) u16, B: [16384,24576)
  const int bid0 = blockIdx.x;
  const int gid = (bid0 & 7) * 32 + (bid0 >> 3);   // 256 blocks
  const int G = gid >> 4, l = gid & 15;
  const int m0 = ((G & 3) * 4 + (l & 3)) * 256;
  const int n0 = ((G >> 2) * 4 + (l >> 2)) * 128;

  const int tid = threadIdx.x, lane = tid & 63, w = tid >> 6;
  const int wm = (w >> 1) * 64, wn = (w & 1) * 64;
  const int lr = lane & 15, g = lane >> 4;
  const int kx = (lr & 7) << 4;

  // staging: chunk ci = l2*512+tid -> (row r = ci>>3, granule gj = ci&7)
  int aoff[4], boff[2];
#pragma unroll
  for (int l2 = 0; l2 < 4; ++l2) {
    int ci = l2 * 512 + tid, r = ci >> 3, gj = ci & 7;
    aoff[l2] = (m0 + r) * 2048 + (gj ^ (r & 7)) * 8;
  }
#pragma unroll
  for (int l2 = 0; l2 < 2; ++l2) {
    int ci = l2 * 512 + tid, r = ci >> 3, gj = ci & 7;
    boff[l2] = (n0 + r) * 2048 + (gj ^ (r & 7)) * 8;
  }
  const int adl = tid * 8;
  const int bdl = 16384 + tid * 8;

  f32x4 acc[4][4];
  const f32x4 zero = {0.f, 0.f, 0.f, 0.f};
#pragma unroll
  for (int ai = 0; ai < 4; ++ai)
#pragma unroll
    for (int bj = 0; bj < 4; ++bj) acc[ai][bj] = zero;

  // prologue: stage tiles 0,1 into slots 0,1
#pragma unroll
  for (int t = 0; t < 2; ++t) {
#pragma unroll
    for (int l2 = 0; l2 < 4; ++l2) gl_lds16(A + aoff[l2] + t * 64, LS[t] + adl + l2 * 4096);
#pragma unroll
    for (int l2 = 0; l2 < 2; ++l2) gl_lds16(B + boff[l2] + t * 64, LS[t] + bdl + l2 * 4096);
  }
  waitvm<6>();
  __builtin_amdgcn_s_barrier();

  int s = 0;
  for (int kt = 0; kt < 32; ++kt) {
    if (kt < 30) {
      const int s2 = (s == 0) ? 2 : s - 1;
      const int k2 = (kt + 2) * 64;
#pragma unroll
      for (int l2 = 0; l2 < 4; ++l2) gl_lds16(A + aoff[l2] + k2, LS[s2] + adl + l2 * 4096);
#pragma unroll
      for (int l2 = 0; l2 < 2; ++l2) gl_lds16(B + boff[l2] + k2, LS[s2] + bdl + l2 * 4096);
    }
    const char* base = (const char*)LS[s];
#pragma unroll
    for (int h = 0; h < 2; ++h) {
      bf16x8 af[4];
#pragma unroll
      for (int ai = 0; ai < 4; ++ai) {
        int r = wm + ai * 16 + lr;
        af[ai] = *(const bf16x8*)(base + r * 128 + ((h * 64 + 16 * g) ^ kx));
      }
      __builtin_amdgcn_s_setprio(1);
#pragma unroll
      for (int bj = 0; bj < 4; ++bj) {
        int rb = wn + bj * 16 + lr;
        bf16x8 bfr = *(const bf16x8*)(base + 32768 + rb * 128 + ((h * 64 + 16 * g) ^ kx));
#pragma unroll
        for (int ai = 0; ai < 4; ++ai)
          acc[ai][bj] = __builtin_amdgcn_mfma_f32_16x16x32_bf16(af[ai], bfr, acc[ai][bj], 0, 0, 0);
      }
      __builtin_amdgcn_s_setprio(0);
    }
    if (kt < 30)       waitvm<6>();
    else if (kt == 30) waitvm<0>();
    __builtin_amdgcn_s_barrier();
    s = (s == 2) ? 0 : s + 1;
  }

  const int rbase = g * 4;
#pragma unroll
  for (int bj = 0; bj < 4; ++bj) {
    const int gn = n0 + wn + bj * 16 + lr;
    const float bv_ = bo[gn];
#pragma unroll
    for (int ai = 0; ai < 4; ++ai)
#pragma unroll
      for (int r = 0; r < 4; ++r) {
        int gm = m0 + wm + ai * 16 + rbase + r;
        outf[(size_t)gm * 2048 + gn] = acc[ai][bj][r] + bv_;
      }
  }
}

// ---------------- flash attention (causal) ----------------
// 512 blocks of 256 threads; bid -> bh = bid&31 (XCD-grouped), qt = 15-(bid>>5)
// (heaviest blocks dispatch first; 2 blocks/CU co-resident at 80KB LDS).
// 4 waves x 32 q-rows; KV tile 64, double-buffered, gl_lds staging pre-swizzled.
// Softmax: per-lane partial row-sums (reduced once at end), defer-max with
// lane-local check (no per-tile shuffles on common path), packed b64 P stores
// in sigma-permuted k-space matching the sigma-permuted V^T.
// Q arrives pre-scaled by 1/sqrt(128)*log2e -> scores in exp2 domain.
__global__ __launch_bounds__(256) void attn_kernel(
    const u16* __restrict__ qg, const u16* __restrict__ kg,
    const u16* __restrict__ vtg, u16* __restrict__ y) {
  __shared__ u16 Kb[2][64 * 128];
  __shared__ u16 Vb[2][128 * 64];
  __shared__ u16 Pl[4][32 * 64];
  const int tid = threadIdx.x, lane = tid & 63, w = tid >> 6;
  const int bid = blockIdx.x;
  const int bh = bid & 31, qt = 15 - (bid >> 5);
  const int b = bh >> 4, h = bh & 15;
  const int lr = lane & 15, lk = (lane >> 4) * 8;
  const u16* Qp = qg + (size_t)bh * (2048 * 128);
  const u16* Kp = kg + (size_t)bh * (2048 * 128);
  const u16* Vp = vtg + (size_t)bh * (128 * 2048);

  int koff[4], voff[4], dstc[4];
#pragma unroll
  for (int c = 0; c < 4; ++c) {
    int ci = c * 256 + tid;
    dstc[c] = ci * 8;
    int kr = ci >> 4, kj = ci & 15;
    koff[c] = kr * 128 + (kj ^ (kr & 7)) * 8;
    int vd = ci >> 3, vj = ci & 7;
    voff[c] = vd * 2048 + (vj ^ (vd & 7)) * 8;
  }
  const int kxor = (lr & 7) << 4;
  const int rbase = (lane >> 4) * 4;
  const f32x4 zero = {0.f, 0.f, 0.f, 0.f};

  const int q0 = qt * 128;
  const int qw = q0 + w * 32;
  const int nt = 2 * qt + 2;

  bf16x8 qf[2][4];
#pragma unroll
  for (int s = 0; s < 2; ++s)
#pragma unroll
    for (int i = 0; i < 4; ++i)
      qf[s][i] = *(const bf16x8*)(Qp + (size_t)(qw + s * 16 + lr) * 128 + i * 32 + lk);

  f32x4 o[2][8];
#pragma unroll
  for (int s = 0; s < 2; ++s)
#pragma unroll
    for (int f = 0; f < 8; ++f) o[s][f] = zero;
  float mrow[2][4], lrow[2][4];
#pragma unroll
  for (int s = 0; s < 2; ++s)
#pragma unroll
    for (int r = 0; r < 4; ++r) { mrow[s][r] = -1e30f; lrow[s][r] = 0.f; }

#pragma unroll
  for (int c = 0; c < 4; ++c) gl_lds16(Kp + koff[c], Kb[0] + dstc[c]);
#pragma unroll
  for (int c = 0; c < 4; ++c) gl_lds16(Vp + voff[c], Vb[0] + dstc[c]);
  __syncthreads();

  int cur = 0;
  for (int t = 0; t < nt; ++t) {
    const int s0 = t * 64;
    if (t + 1 < nt) {
      const size_t skn = (size_t)(s0 + 64) * 128;
#pragma unroll
      for (int c = 0; c < 4; ++c) gl_lds16(Kp + skn + koff[c], Kb[cur ^ 1] + dstc[c]);
#pragma unroll
      for (int c = 0; c < 4; ++c) gl_lds16(Vp + (s0 + 64) + voff[c], Vb[cur ^ 1] + dstc[c]);
    }
    if (s0 <= qw + 31) {
      const char* Kc = (const char*)Kb[cur];
      f32x4 sf[2][4];
      __builtin_amdgcn_s_setprio(1);
#pragma unroll
      for (int sj = 0; sj < 4; ++sj) {
        f32x4 a0 = zero, a1 = zero;
#pragma unroll
        for (int i = 0; i < 4; ++i) {
          bf16x8 kf = *(const bf16x8*)(Kc + ((((sj * 16 + lr) * 256) + (i * 32 + lk) * 2) ^ kxor));
          a0 = __builtin_amdgcn_mfma_f32_16x16x32_bf16(qf[0][i], kf, a0, 0, 0, 0);
          a1 = __builtin_amdgcn_mfma_f32_16x16x32_bf16(qf[1][i], kf, a1, 0, 0, 0);
        }
        sf[0][sj] = a0; sf[1][sj] = a1;
      }
      __builtin_amdgcn_s_setprio(0);

      char* Pc = (char*)Pl[w];
      const bool diag = (s0 + 63 > qw);
      float pmax[2][4];
      bool need = false;
#pragma unroll
      for (int s = 0; s < 2; ++s)
#pragma unroll
        for (int r = 0; r < 4; ++r) {
          if (diag) {
            const int rq = qw + s * 16 + rbase + r;
#pragma unroll
            for (int sj = 0; sj < 4; ++sj)
              if (s0 + sj * 16 + lr > rq) sf[s][sj][r] = -1e30f;
          }
          float pm = fmaxf(fmaxf(sf[s][0][r], sf[s][1][r]),
                           fmaxf(sf[s][2][r], sf[s][3][r]));
          pmax[s][r] = pm;
          need |= (pm > mrow[s][r] + 8.f);
        }
      if (__any(need)) {
#pragma unroll
        for (int s = 0; s < 2; ++s)
#pragma unroll
          for (int r = 0; r < 4; ++r) {
            float pm = pmax[s][r];
            pm = fmaxf(pm, __shfl_xor(pm, 1));
            pm = fmaxf(pm, __shfl_xor(pm, 2));
            pm = fmaxf(pm, __shfl_xor(pm, 4));
            pm = fmaxf(pm, __shfl_xor(pm, 8));
            float mnew = fmaxf(mrow[s][r], pm);
            float sfac = __builtin_amdgcn_exp2f(mrow[s][r] - mnew);
            mrow[s][r] = mnew;
            lrow[s][r] *= sfac;
#pragma unroll
            for (int f = 0; f < 8; ++f) o[s][f][r] *= sfac;
          }
      }
#pragma unroll
      for (int s = 0; s < 2; ++s)
#pragma unroll
        for (int r = 0; r < 4; ++r) {
          const int prow = s * 16 + rbase + r;
          u16x4 pk;
          float ps = 0.f;
#pragma unroll
          for (int sj = 0; sj < 4; ++sj) {
            float p = __builtin_amdgcn_exp2f(sf[s][sj][r] - mrow[s][r]);
            ps += p;
            pk[sj] = f2b(p);
          }
          lrow[s][r] += ps;
          *(u16x4*)(Pc + ((prow * 128 + lr * 8) ^ ((prow & 7) << 4))) = pk;
        }

      const char* Vc = (const char*)Vb[cur];
      __builtin_amdgcn_s_setprio(1);
#pragma unroll
      for (int st = 0; st < 2; ++st) {
        bf16x8 pf0 = *(const bf16x8*)(Pc + (((lr * 128) + (st * 32 + lk) * 2) ^ kxor));
        bf16x8 pf1 = *(const bf16x8*)(Pc + ((((16 + lr) * 128) + (st * 32 + lk) * 2) ^ kxor));
#pragma unroll
        for (int f = 0; f < 8; ++f) {
          bf16x8 vf = *(const bf16x8*)(Vc + ((((f * 16 + lr) * 128) + (st * 32 + lk) * 2) ^ kxor));
          o[0][f] = __builtin_amdgcn_mfma_f32_16x16x32_bf16(pf0, vf, o[0][f], 0, 0, 0);
          o[1][f] = __builtin_amdgcn_mfma_f32_16x16x32_bf16(pf1, vf, o[1][f], 0, 0, 0);
        }
      }
      __builtin_amdgcn_s_setprio(0);
    }
    __syncthreads();
    cur ^= 1;
  }

#pragma unroll
  for (int s = 0; s < 2; ++s)
#pragma unroll
    for (int r = 0; r < 4; ++r) {
      float l = lrow[s][r];
      l += __shfl_xor(l, 1);
      l += __shfl_xor(l, 2);
      l += __shfl_xor(l, 4);
      l += __shfl_xor(l, 8);
      const float rinv = __builtin_amdgcn_rcpf(l);
      const int row = qw + s * 16 + rbase + r;
#pragma unroll
      for (int f = 0; f < 8; ++f)
        y[((size_t)b * 2048 + row) * 2048 + h * 128 + f * 16 + lr] =
            f2b(o[s][f][r] * rinv);
    }
}

// ---------------- launch ----------------

extern "C" void kernel_launch(void* const* d_in, const int* in_sizes, int n_in,
                              void* d_out, int out_size, void* d_ws, size_t ws_size,
                              hipStream_t stream) {
  const float* x  = (const float*)d_in[0];
  const float* Wq = (const float*)d_in[1];
  const float* bq = (const float*)d_in[2];
  const float* Wk = (const float*)d_in[3];
  const float* bk = (const float*)d_in[4];
  const float* Wv = (const float*)d_in[5];
  const float* bv = (const float*)d_in[6];
  const float* Wo = (const float*)d_in[7];
  const float* bo = (const float*)d_in[8];
  float* out = (float*)d_out;
  char* ws = (char*)d_ws;

  u16* xb  = (u16*)(ws + 0);          // 16 MB; reused as yb after QKV GEMM
  u16* Wt  = (u16*)(ws + 16777216);   // 24 MB; front 8 MB reused as Wot, next 16 MB as vtb
  u16* qb  = (u16*)(ws + 41943040);   // 16 MB
  u16* kb  = (u16*)(ws + 58720256);   // 16 MB
  u16* vb  = (u16*)(ws + 75497472);   // 16 MB (total 88 MB)
  u16* Wot = Wt;                      // [2048][2048] bf16 = 8 MB
  u16* vtb = (u16*)(ws + 25165824);   // [B,H,128,T] bf16 = 16 MB
  u16* yb  = xb;

  cast_x_kernel<<<8192, 256, 0, stream>>>(x, xb, M_TOT * D_MODEL);
  trans_wqkv_kernel<<<dim3(32, 48), 256, 0, stream>>>(Wq, Wk, Wv, Wt);
  gemm_qkv_kernel<<<256, 512, 0, stream>>>(xb, Wt, qb, kb, vb, bq, bk, bv);
  trans_wo_kernel<<<dim3(32, 16), 256, 0, stream>>>(Wo, Wot);
  transpose_v_kernel<<<dim3(32, 32), 256, 0, stream>>>(vb, vtb);
  attn_kernel<<<512, 256, 0, stream>>>(qb, kb, vtb, yb);
  gemm_out_kernel<<<256, 512, 0, stream>>>(yb, Wot, out, bo);
}

// Round 10
// 282.844 us; speedup vs baseline: 1.0968x; 1.0004x over previous
//
#include <hip/hip_runtime.h>
#include <stdint.h>

typedef unsigned short u16;
typedef __attribute__((ext_vector_type(4))) u16 u16x4;
typedef __attribute__((ext_vector_type(8))) u16 u16x8;
typedef __attribute__((ext_vector_type(8))) __bf16 bf16x8;
typedef __attribute__((ext_vector_type(4))) float f32x4;
typedef __attribute__((ext_vector_type(16))) float f32x16;

#define D_MODEL 2048
#define N_HEADS 16
#define HEAD_DIM 128
#define BATCH 2
#define SEQ 2048
#define M_TOT (BATCH*SEQ)          // 4096
#define N_QKV (3*D_MODEL)          // 6144

__device__ __forceinline__ u16 f2b(float f) {
  union { float f; uint32_t u; } c; c.f = f;
  uint32_t u = c.u;
  uint32_t r = (u + 0x7fffu + ((u >> 16) & 1u)) >> 16;
  return (u16)r;
}

__device__ __forceinline__ void gl_lds16(const u16* g, u16* l) {
  __builtin_amdgcn_global_load_lds(
      (const __attribute__((address_space(1))) uint32_t*)g,
      (__attribute__((address_space(3))) uint32_t*)l, 16, 0, 0);
}

template <int N> __device__ __forceinline__ void waitvm() {
  if constexpr (N == 6)      asm volatile("s_waitcnt vmcnt(6)" ::: "memory");
  else if constexpr (N == 5) asm volatile("s_waitcnt vmcnt(5)" ::: "memory");
  else                       asm volatile("s_waitcnt vmcnt(0)" ::: "memory");
}

// ---------------- prep kernels ----------------

__global__ void cast_x_kernel(const float* __restrict__ x, u16* __restrict__ xb, int n) {
  int i = (blockIdx.x * blockDim.x + threadIdx.x) * 4;
  if (i >= n) return;
  f32x4 v = *(const f32x4*)(x + i);
  u16x4 o;
  o[0] = f2b(v[0]); o[1] = f2b(v[1]); o[2] = f2b(v[2]); o[3] = f2b(v[3]);
  *(u16x4*)(xb + i) = o;
}

// Wq/Wk/Wv [H][2048][128] f32  ->  Wt [6144][2048] bf16, row n=(qkv*2048+h*128+d), K-major
__global__ void trans_wqkv_kernel(const float* __restrict__ Wq, const float* __restrict__ Wk,
                                  const float* __restrict__ Wv, u16* __restrict__ Wt) {
  __shared__ u16 Tl[128][72];
  const int hh = blockIdx.y;           // 0..47 = qkv*16+h
  const int qkv = hh >> 4, h = hh & 15;
  const float* src = (qkv == 0 ? Wq : qkv == 1 ? Wk : Wv) + (size_t)h * 2048 * 128;
  const int k0 = blockIdx.x * 64;
  const int tid = threadIdx.x;
  for (int it = 0; it < 32; ++it) {
    int idx = it * 256 + tid;
    int k = idx >> 7, d = idx & 127;
    Tl[d][k] = f2b(src[(size_t)(k0 + k) * 128 + d]);
  }
  __syncthreads();
  for (int it = 0; it < 32; ++it) {
    int idx = it * 256 + tid;
    int d = idx >> 6, kk = idx & 63;
    Wt[(size_t)(hh * 128 + d) * 2048 + k0 + kk] = Tl[d][kk];
  }
}

// Wo [2048][2048] f32 -> Wot [2048][2048] bf16 (transposed, K-major)
__global__ void trans_wo_kernel(const float* __restrict__ Wo, u16* __restrict__ Wot) {
  __shared__ u16 Tl[128][72];
  const int k0 = blockIdx.x * 64;     // 32 tiles
  const int n0 = blockIdx.y * 128;    // 16 tiles
  const int tid = threadIdx.x;
  for (int it = 0; it < 32; ++it) {
    int idx = it * 256 + tid;
    int k = idx >> 7, n = idx & 127;
    Tl[n][k] = f2b(Wo[(size_t)(k0 + k) * 2048 + n0 + n]);
  }
  __syncthreads();
  for (int it = 0; it < 32; ++it) {
    int idx = it * 256 + tid;
    int d = idx >> 6, kk = idx & 63;
    Wot[(size_t)(n0 + d) * 2048 + k0 + kk] = Tl[d][kk];
  }
}

// vb [B,H,T,128] bf16 -> vt [B,H,128,T] bf16 with sigma-permuted columns within
// each 64-tile: sigma(t) = (t&15)*4 + (t>>4). Matches attn's packed-P k-space.
__global__ void transpose_v_kernel(const u16* __restrict__ vb, u16* __restrict__ vt) {
  __shared__ u16 Tl[128 * 65];
  const int bh = blockIdx.y;
  const int t0 = blockIdx.x * 64;
  const int tid = threadIdx.x;
  const u16* src = vb + (size_t)bh * 2048 * 128;
  u16* dstp = vt + (size_t)bh * 128 * 2048;
#pragma unroll
  for (int c = 0; c < 4; ++c) {
    int ci = c * 256 + tid;
    int tr = ci >> 4, d0 = (ci & 15) * 8;
    u16x8 v = *(const u16x8*)(src + (size_t)(t0 + tr) * 128 + d0);
#pragma unroll
    for (int e = 0; e < 8; ++e) Tl[(d0 + e) * 65 + tr] = v[e];
  }
  __syncthreads();
#pragma unroll
  for (int it = 0; it < 32; ++it) {
    int idx = it * 256 + tid;
    int d = idx >> 6, tt = idx & 63;
    dstp[(size_t)d * 2048 + t0 + ((tt & 15) * 4 + (tt >> 4))] = Tl[d * 65 + tt];
  }
}

// ---------- QKV GEMM: 256x384 tile, 32x32x16 MFMA, BK=32, ring-3, counted vmcnt ----------
// 512 thr = 8 waves (2M x 4N), wave tile 128x96 = 4x3 32x32 fragments (acc 192 f32/lane).
// LDS: 3 ring slots of {A[256][32], B[384][32]} bf16 (40 KB each, 120 KB total).
// Row-pair interleaved layout (kills the 4-way conflict of 64-B rows under 32-row
// b128 sweeps): granule g of row r lives at slot s = (r>>1)*8 + (x ^ ((r>>1)&7)),
// x = ((r&1)<<2)|g  -- a 3-bit XOR over the 8 granules of each 128-B row pair.
// 32-row sweep -> every 16-lane phase covers all 8 bank-bases 2x (= free profile).
// Staging dests tid*16-linear (rule-21 safe); source address inverts the map.
// Tile kt reads slot kt%3 and stages tile kt+2 (5 gl_lds/thread); end-of-tile
// s_waitcnt vmcnt(5) -> tile kt+1 landed, kt+2 in flight. Never 0 until drain.
__global__ __launch_bounds__(512, 2) void gemm_qkv_kernel(
    const u16* __restrict__ A, const u16* __restrict__ B,
    u16* __restrict__ qo, u16* __restrict__ ko, u16* __restrict__ vo,
    const float* __restrict__ bq, const float* __restrict__ bk, const float* __restrict__ bv) {
  __shared__ u16 LS[3][20480];   // A: [0,8192) u16, B: [8192,20480)
  const int bid0 = blockIdx.x;
  const int gid = (bid0 & 7) * 32 + (bid0 >> 3);   // XCD-chunked (256 blocks)
  const int G = gid >> 4, l = gid & 15;            // 16 groups of 4mt x 4nt
  const int m0 = ((G & 3) * 4 + (l & 3)) * 256;
  const int n0 = ((G >> 2) * 4 + (l >> 2)) * 384;

  const int tid = threadIdx.x, lane = tid & 63, w = tid >> 6;
  const int wm = (w >> 2) * 128, wn = (w & 3) * 96;
  const int l31 = lane & 31, g2 = lane >> 5;

  // staging source: chunk ci holds (r = 2*(ci>>3) + (x>>2), g = x&3), x = (ci&7)^((ci>>3)&7)
  int aoff[2], boff[3];
#pragma unroll
  for (int l2 = 0; l2 < 2; ++l2) {
    int ci = l2 * 512 + tid, t = ci >> 3, x = (ci & 7) ^ (t & 7);
    aoff[l2] = (m0 + 2 * t + (x >> 2)) * 2048 + (x & 3) * 8;
  }
#pragma unroll
  for (int l2 = 0; l2 < 3; ++l2) {
    int ci = l2 * 512 + tid, t = ci >> 3, x = (ci & 7) ^ (t & 7);
    boff[l2] = (n0 + 2 * t + (x >> 2)) * 2048 + (x & 3) * 8;
  }
  const int adl = tid * 8;
  const int bdl = 8192 + tid * 8;

  f32x16 acc[4][3];
#pragma unroll
  for (int ai = 0; ai < 4; ++ai)
#pragma unroll
    for (int bj = 0; bj < 3; ++bj)
#pragma unroll
      for (int e = 0; e < 16; ++e) acc[ai][bj][e] = 0.f;

  // prologue: stage tiles 0,1 into slots 0,1
#pragma unroll
  for (int t = 0; t < 2; ++t) {
#pragma unroll
    for (int l2 = 0; l2 < 2; ++l2) gl_lds16(A + aoff[l2] + t * 32, LS[t] + adl + l2 * 4096);
#pragma unroll
    for (int l2 = 0; l2 < 3; ++l2) gl_lds16(B + boff[l2] + t * 32, LS[t] + bdl + l2 * 4096);
  }
  waitvm<5>();
  __builtin_amdgcn_s_barrier();

  int s = 0;
  for (int kt = 0; kt < 64; ++kt) {
    if (kt < 62) {
      const int s2 = (s == 0) ? 2 : s - 1;
      const int k2 = (kt + 2) * 32;
#pragma unroll
      for (int l2 = 0; l2 < 2; ++l2) gl_lds16(A + aoff[l2] + k2, LS[s2] + adl + l2 * 4096);
#pragma unroll
      for (int l2 = 0; l2 < 3; ++l2) gl_lds16(B + boff[l2] + k2, LS[s2] + bdl + l2 * 4096);
    }
    const char* base = (const char*)LS[s];
#pragma unroll
    for (int kk = 0; kk < 2; ++kk) {
      bf16x8 af[4];
#pragma unroll
      for (int ai = 0; ai < 4; ++ai) {
        int r = wm + ai * 32 + l31;
        int x = ((r & 1) << 2) | (2 * kk + g2);
        af[ai] = *(const bf16x8*)(base + (r >> 1) * 128 + 16 * (x ^ ((r >> 1) & 7)));
      }
      __builtin_amdgcn_s_setprio(1);
#pragma unroll
      for (int bj = 0; bj < 3; ++bj) {
        int rb = wn + bj * 32 + l31;
        int xb2 = ((rb & 1) << 2) | (2 * kk + g2);
        bf16x8 bfr = *(const bf16x8*)(base + 16384 + (rb >> 1) * 128 + 16 * (xb2 ^ ((rb >> 1) & 7)));
#pragma unroll
        for (int ai = 0; ai < 4; ++ai)
          acc[ai][bj] = __builtin_amdgcn_mfma_f32_32x32x16_bf16(af[ai], bfr, acc[ai][bj], 0, 0, 0);
      }
      __builtin_amdgcn_s_setprio(0);
    }
    if (kt < 62)       waitvm<5>();
    else if (kt == 62) waitvm<0>();
    __builtin_amdgcn_s_barrier();
    s = (s == 2) ? 0 : s + 1;
  }

  // epilogue: C/D 32x32 layout col=lane&31, row=(reg&3)+8*(reg>>2)+4*(lane>>5)
  const float qscale = 0.08838834764831845f * 1.4426950408889634f;  // 1/sqrt(128)*log2e
#pragma unroll
  for (int bj = 0; bj < 3; ++bj) {
    const int n = n0 + wn + bj * 32 + l31;
    const int qkv = n >> 11, hh = (n >> 7) & 15, d = n & 127;
    const float* bias = (qkv == 0) ? bq : (qkv == 1) ? bk : bv;
    u16* dst = (qkv == 0) ? qo : (qkv == 1) ? ko : vo;
    const float bv_ = bias[n & 2047];
#pragma unroll
    for (int ai = 0; ai < 4; ++ai)
#pragma unroll
      for (int e = 0; e < 16; ++e) {
        int row = (e & 3) + 8 * (e >> 2) + 4 * g2;
        int gm = m0 + wm + ai * 32 + row;
        float val = acc[ai][bj][e] + bv_;
        if (qkv == 0) val *= qscale;
        int b = gm >> 11, t = gm & 2047;
        dst[((size_t)(b * 16 + hh) * 2048 + t) * 128 + d] = f2b(val);
      }
  }
}

// ---------- Output GEMM: 256x128 tile, 16x16x32 MFMA, BK=64, ring-3, counted vmcnt ----------
// 512 thr = 8 waves (4M x 2N), wave 64x64 = 4x4 16x16 frags (acc 64 f32/lane).
// LDS: 3 ring slots of {A[256][64], B[128][64]} bf16 (48 KB each, 144 KB).
// Staging dests tid*8-linear (rule-21 safe); source pre-swizzled with full
// granule XOR gj ^ (row&7) within the 8-granule 128-B row (2-way = free reads).
// Tile kt reads slot kt%3, stages kt+2 (6 loads/thread); vmcnt(6) per tile.
__global__ __launch_bounds__(512, 2) void gemm_out_kernel(
    const u16* __restrict__ A, const u16* __restrict__ B,
    float* __restrict__ outf, const float* __restrict__ bo) {
  __shared__ u16 LS[3][24576];   // A: [0,16384) u16, B: [16384,24576)
  const int bid0 = blockIdx.x;
  const int gid = (bid0 & 7) * 32 + (bid0 >> 3);   // 256 blocks
  const int G = gid >> 4, l = gid & 15;
  const int m0 = ((G & 3) * 4 + (l & 3)) * 256;
  const int n0 = ((G >> 2) * 4 + (l >> 2)) * 128;

  const int tid = threadIdx.x, lane = tid & 63, w = tid >> 6;
  const int wm = (w >> 1) * 64, wn = (w & 1) * 64;
  const int lr = lane & 15, g = lane >> 4;
  const int kx = (lr & 7) << 4;

  // staging: chunk ci = l2*512+tid -> (row r = ci>>3, granule gj = ci&7)
  int aoff[4], boff[2];
#pragma unroll
  for (int l2 = 0; l2 < 4; ++l2) {
    int ci = l2 * 512 + tid, r = ci >> 3, gj = ci & 7;
    aoff[l2] = (m0 + r) * 2048 + (gj ^ (r & 7)) * 8;
  }
#pragma unroll
  for (int l2 = 0; l2 < 2; ++l2) {
    int ci = l2 * 512 + tid, r = ci >> 3, gj = ci & 7;
    boff[l2] = (n0 + r) * 2048 + (gj ^ (r & 7)) * 8;
  }
  const int adl = tid * 8;
  const int bdl = 16384 + tid * 8;

  f32x4 acc[4][4];
  const f32x4 zero = {0.f, 0.f, 0.f, 0.f};
#pragma unroll
  for (int ai = 0; ai < 4; ++ai)
#pragma unroll
    for (int bj = 0; bj < 4; ++bj) acc[ai][bj] = zero;

  // prologue: stage tiles 0,1 into slots 0,1
#pragma unroll
  for (int t = 0; t < 2; ++t) {
#pragma unroll
    for (int l2 = 0; l2 < 4; ++l2) gl_lds16(A + aoff[l2] + t * 64, LS[t] + adl + l2 * 4096);
#pragma unroll
    for (int l2 = 0; l2 < 2; ++l2) gl_lds16(B + boff[l2] + t * 64, LS[t] + bdl + l2 * 4096);
  }
  waitvm<6>();
  __builtin_amdgcn_s_barrier();

  int s = 0;
  for (int kt = 0; kt < 32; ++kt) {
    if (kt < 30) {
      const int s2 = (s == 0) ? 2 : s - 1;
      const int k2 = (kt + 2) * 64;
#pragma unroll
      for (int l2 = 0; l2 < 4; ++l2) gl_lds16(A + aoff[l2] + k2, LS[s2] + adl + l2 * 4096);
#pragma unroll
      for (int l2 = 0; l2 < 2; ++l2) gl_lds16(B + boff[l2] + k2, LS[s2] + bdl + l2 * 4096);
    }
    const char* base = (const char*)LS[s];
#pragma unroll
    for (int h = 0; h < 2; ++h) {
      bf16x8 af[4];
#pragma unroll
      for (int ai = 0; ai < 4; ++ai) {
        int r = wm + ai * 16 + lr;
        af[ai] = *(const bf16x8*)(base + r * 128 + ((h * 64 + 16 * g) ^ kx));
      }
      __builtin_amdgcn_s_setprio(1);
#pragma unroll
      for (int bj = 0; bj < 4; ++bj) {
        int rb = wn + bj * 16 + lr;
        bf16x8 bfr = *(const bf16x8*)(base + 32768 + rb * 128 + ((h * 64 + 16 * g) ^ kx));
#pragma unroll
        for (int ai = 0; ai < 4; ++ai)
          acc[ai][bj] = __builtin_amdgcn_mfma_f32_16x16x32_bf16(af[ai], bfr, acc[ai][bj], 0, 0, 0);
      }
      __builtin_amdgcn_s_setprio(0);
    }
    if (kt < 30)       waitvm<6>();
    else if (kt == 30) waitvm<0>();
    __builtin_amdgcn_s_barrier();
    s = (s == 2) ? 0 : s + 1;
  }

  const int rbase = g * 4;
#pragma unroll
  for (int bj = 0; bj < 4; ++bj) {
    const int gn = n0 + wn + bj * 16 + lr;
    const float bv_ = bo[gn];
#pragma unroll
    for (int ai = 0; ai < 4; ++ai)
#pragma unroll
      for (int r = 0; r < 4; ++r) {
        int gm = m0 + wm + ai * 16 + rbase + r;
        outf[(size_t)gm * 2048 + gn] = acc[ai][bj][r] + bv_;
      }
  }
}

// ---------------- flash attention (causal) ----------------
// 512 blocks of 256 threads; bid -> bh = bid&31 (XCD-grouped), qt = 15-(bid>>5)
// (heaviest blocks dispatch first; 2 blocks/CU co-resident at 80KB LDS).
// 4 waves x 32 q-rows; KV tile 64, double-buffered, gl_lds staging pre-swizzled.
// Softmax: per-lane partial row-sums (reduced once at end), defer-max with
// lane-local check (no per-tile shuffles on common path), packed b64 P stores
// in sigma-permuted k-space matching the sigma-permuted V^T.
// Q arrives pre-scaled by 1/sqrt(128)*log2e -> scores in exp2 domain.
__global__ __launch_bounds__(256) void attn_kernel(
    const u16* __restrict__ qg, const u16* __restrict__ kg,
    const u16* __restrict__ vtg, u16* __restrict__ y) {
  __shared__ u16 Kb[2][64 * 128];
  __shared__ u16 Vb[2][128 * 64];
  __shared__ u16 Pl[4][32 * 64];
  const int tid = threadIdx.x, lane = tid & 63, w = tid >> 6;
  const int bid = blockIdx.x;
  const int bh = bid & 31, qt = 15 - (bid >> 5);
  const int b = bh >> 4, h = bh & 15;
  const int lr = lane & 15, lk = (lane >> 4) * 8;
  const u16* Qp = qg + (size_t)bh * (2048 * 128);
  const u16* Kp = kg + (size_t)bh * (2048 * 128);
  const u16* Vp = vtg + (size_t)bh * (128 * 2048);

  int koff[4], voff[4], dstc[4];
#pragma unroll
  for (int c = 0; c < 4; ++c) {
    int ci = c * 256 + tid;
    dstc[c] = ci * 8;
    int kr = ci >> 4, kj = ci & 15;
    koff[c] = kr * 128 + (kj ^ (kr & 7)) * 8;
    int vd = ci >> 3, vj = ci & 7;
    voff[c] = vd * 2048 + (vj ^ (vd & 7)) * 8;
  }
  const int kxor = (lr & 7) << 4;
  const int rbase = (lane >> 4) * 4;
  const f32x4 zero = {0.f, 0.f, 0.f, 0.f};

  const int q0 = qt * 128;
  const int qw = q0 + w * 32;
  const int nt = 2 * qt + 2;

  bf16x8 qf[2][4];
#pragma unroll
  for (int s = 0; s < 2; ++s)
#pragma unroll
    for (int i = 0; i < 4; ++i)
      qf[s][i] = *(const bf16x8*)(Qp + (size_t)(qw + s * 16 + lr) * 128 + i * 32 + lk);

  f32x4 o[2][8];
#pragma unroll
  for (int s = 0; s < 2; ++s)
#pragma unroll
    for (int f = 0; f < 8; ++f) o[s][f] = zero;
  float mrow[2][4], lrow[2][4];
#pragma unroll
  for (int s = 0; s < 2; ++s)
#pragma unroll
    for (int r = 0; r < 4; ++r) { mrow[s][r] = -1e30f; lrow[s][r] = 0.f; }

#pragma unroll
  for (int c = 0; c < 4; ++c) gl_lds16(Kp + koff[c], Kb[0] + dstc[c]);
#pragma unroll
  for (int c = 0; c < 4; ++c) gl_lds16(Vp + voff[c], Vb[0] + dstc[c]);
  __syncthreads();

  int cur = 0;
  for (int t = 0; t < nt; ++t) {
    const int s0 = t * 64;
    if (t + 1 < nt) {
      const size_t skn = (size_t)(s0 + 64) * 128;
#pragma unroll
      for (int c = 0; c < 4; ++c) gl_lds16(Kp + skn + koff[c], Kb[cur ^ 1] + dstc[c]);
#pragma unroll
      for (int c = 0; c < 4; ++c) gl_lds16(Vp + (s0 + 64) + voff[c], Vb[cur ^ 1] + dstc[c]);
    }
    if (s0 <= qw + 31) {
      const char* Kc = (const char*)Kb[cur];
      f32x4 sf[2][4];
      __builtin_amdgcn_s_setprio(1);
#pragma unroll
      for (int sj = 0; sj < 4; ++sj) {
        f32x4 a0 = zero, a1 = zero;
#pragma unroll
        for (int i = 0; i < 4; ++i) {
          bf16x8 kf = *(const bf16x8*)(Kc + ((((sj * 16 + lr) * 256) + (i * 32 + lk) * 2) ^ kxor));
          a0 = __builtin_amdgcn_mfma_f32_16x16x32_bf16(qf[0][i], kf, a0, 0, 0, 0);
          a1 = __builtin_amdgcn_mfma_f32_16x16x32_bf16(qf[1][i], kf, a1, 0, 0, 0);
        }
        sf[0][sj] = a0; sf[1][sj] = a1;
      }
      __builtin_amdgcn_s_setprio(0);

      char* Pc = (char*)Pl[w];
      const bool diag = (s0 + 63 > qw);
      float pmax[2][4];
      bool need = false;
#pragma unroll
      for (int s = 0; s < 2; ++s)
#pragma unroll
        for (int r = 0; r < 4; ++r) {
          if (diag) {
            const int rq = qw + s * 16 + rbase + r;
#pragma unroll
            for (int sj = 0; sj < 4; ++sj)
              if (s0 + sj * 16 + lr > rq) sf[s][sj][r] = -1e30f;
          }
          float pm = fmaxf(fmaxf(sf[s][0][r], sf[s][1][r]),
                           fmaxf(sf[s][2][r], sf[s][3][r]));
          pmax[s][r] = pm;
          need |= (pm > mrow[s][r] + 8.f);
        }
      if (__any(need)) {
#pragma unroll
        for (int s = 0; s < 2; ++s)
#pragma unroll
          for (int r = 0; r < 4; ++r) {
            float pm = pmax[s][r];
            pm = fmaxf(pm, __shfl_xor(pm, 1));
            pm = fmaxf(pm, __shfl_xor(pm, 2));
            pm = fmaxf(pm, __shfl_xor(pm, 4));
            pm = fmaxf(pm, __shfl_xor(pm, 8));
            float mnew = fmaxf(mrow[s][r], pm);
            float sfac = __builtin_amdgcn_exp2f(mrow[s][r] - mnew);
            mrow[s][r] = mnew;
            lrow[s][r] *= sfac;
#pragma unroll
            for (int f = 0; f < 8; ++f) o[s][f][r] *= sfac;
          }
      }
#pragma unroll
      for (int s = 0; s < 2; ++s)
#pragma unroll
        for (int r = 0; r < 4; ++r) {
          const int prow = s * 16 + rbase + r;
          u16x4 pk;
          float ps = 0.f;
#pragma unroll
          for (int sj = 0; sj < 4; ++sj) {
            float p = __builtin_amdgcn_exp2f(sf[s][sj][r] - mrow[s][r]);
            ps += p;
            pk[sj] = f2b(p);
          }
          lrow[s][r] += ps;
          *(u16x4*)(Pc + ((prow * 128 + lr * 8) ^ ((prow & 7) << 4))) = pk;
        }

      const char* Vc = (const char*)Vb[cur];
      __builtin_amdgcn_s_setprio(1);
#pragma unroll
      for (int st = 0; st < 2; ++st) {
        bf16x8 pf0 = *(const bf16x8*)(Pc + (((lr * 128) + (st * 32 + lk) * 2) ^ kxor));
        bf16x8 pf1 = *(const bf16x8*)(Pc + ((((16 + lr) * 128) + (st * 32 + lk) * 2) ^ kxor));
#pragma unroll
        for (int f = 0; f < 8; ++f) {
          bf16x8 vf = *(const bf16x8*)(Vc + ((((f * 16 + lr) * 128) + (st * 32 + lk) * 2) ^ kxor));
          o[0][f] = __builtin_amdgcn_mfma_f32_16x16x32_bf16(pf0, vf, o[0][f], 0, 0, 0);
          o[1][f] = __builtin_amdgcn_mfma_f32_16x16x32_bf16(pf1, vf, o[1][f], 0, 0, 0);
        }
      }
      __builtin_amdgcn_s_setprio(0);
    }
    __syncthreads();
    cur ^= 1;
  }

#pragma unroll
  for (int s = 0; s < 2; ++s)
#pragma unroll
    for (int r = 0; r < 4; ++r) {
      float l = lrow[s][r];
      l += __shfl_xor(l, 1);
      l += __shfl_xor(l, 2);
      l += __shfl_xor(l, 4);
      l += __shfl_xor(l, 8);
      const float rinv = __builtin_amdgcn_rcpf(l);
      const int row = qw + s * 16 + rbase + r;
#pragma unroll
      for (int f = 0; f < 8; ++f)
        y[((size_t)b * 2048 + row) * 2048 + h * 128 + f * 16 + lr] =
            f2b(o[s][f][r] * rinv);
    }
}

// ---------------- launch ----------------

extern "C" void kernel_launch(void* const* d_in, const int* in_sizes, int n_in,
                              void* d_out, int out_size, void* d_ws, size_t ws_size,
                              hipStream_t stream) {
  const float* x  = (const float*)d_in[0];
  const float* Wq = (const float*)d_in[1];
  const float* bq = (const float*)d_in[2];
  const float* Wk = (const float*)d_in[3];
  const float* bk = (const float*)d_in[4];
  const float* Wv = (const float*)d_in[5];
  const float* bv = (const float*)d_in[6];
  const float* Wo = (const float*)d_in[7];
  const float* bo = (const float*)d_in[8];
  float* out = (float*)d_out;
  char* ws = (char*)d_ws;

  u16* xb  = (u16*)(ws + 0);          // 16 MB; reused as yb after QKV GEMM
  u16* Wt  = (u16*)(ws + 16777216);   // 24 MB; front 8 MB reused as Wot, next 16 MB as vtb
  u16* qb  = (u16*)(ws + 41943040);   // 16 MB
  u16* kb  = (u16*)(ws + 58720256);   // 16 MB
  u16* vb  = (u16*)(ws + 75497472);   // 16 MB (total 88 MB)
  u16* Wot = Wt;                      // [2048][2048] bf16 = 8 MB
  u16* vtb = (u16*)(ws + 25165824);   // [B,H,128,T] bf16 = 16 MB
  u16* yb  = xb;

  cast_x_kernel<<<8192, 256, 0, stream>>>(x, xb, M_TOT * D_MODEL);
  trans_wqkv_kernel<<<dim3(32, 48), 256, 0, stream>>>(Wq, Wk, Wv, Wt);
  gemm_qkv_kernel<<<256, 512, 0, stream>>>(xb, Wt, qb, kb, vb, bq, bk, bv);
  trans_wo_kernel<<<dim3(32, 16), 256, 0, stream>>>(Wo, Wot);
  transpose_v_kernel<<<dim3(32, 32), 256, 0, stream>>>(vb, vtb);
  attn_kernel<<<512, 256, 0, stream>>>(qb, kb, vtb, yb);
  gemm_out_kernel<<<256, 512, 0, stream>>>(yb, Wot, out, bo);
}